// Round 4
// baseline (7174.460 us; speedup 1.0000x reference)
//
#include <hip/hip_runtime.h>
#include <hip/hip_bf16.h>

typedef unsigned short ushort_t;
typedef __attribute__((ext_vector_type(8))) short short8;   // 8 bf16 = 4 VGPRs
typedef __attribute__((ext_vector_type(4))) float f32x4;    // MFMA C/D

#define N_NODES 20000
#define N_EDGES 320000
#define F_NODE 64
#define F_EDGE 16
#define HID 300
#define HP 320          // padded hidden (K and row stride of h), 10 chunks of 32
#define NPAD 304        // padded N (19 n-tiles of 16)
#define DEPTH 3
#define N_GRAPHS 128

#define WFRAG_USHORT_PER_LAYER (10 * 19 * 64 * 8)  // 97280 ushorts = 194560 B
#define WCHUNK_USHORT (19 * 64 * 8)                // 9728 ushorts  = 19456 B

__device__ __forceinline__ float bf2f(ushort_t u) {
    union { unsigned int i; float f; } v;
    v.i = ((unsigned int)u) << 16;
    return v.f;
}
__device__ __forceinline__ ushort_t f2bf(float f) {
    union { float f; unsigned int i; } v;
    v.f = f;
    unsigned int x = v.i;
    unsigned int r = x + 0x7fffu + ((x >> 16) & 1u);  // RNE
    return (ushort_t)(r >> 16);
}

// ---------------- CSR build (col -> node adjacency) ----------------
__global__ __launch_bounds__(256) void csr_hist(
    const int* __restrict__ col, int* __restrict__ deg)
{
    int e = blockIdx.x * 256 + threadIdx.x;
    atomicAdd(&deg[col[e]], 1);
}

__global__ __launch_bounds__(256) void csr_scan(
    const int* __restrict__ deg, int* __restrict__ offsets,
    int* __restrict__ cursor)
{
    __shared__ int sums[256];
    const int t = threadIdx.x;
    const int CH = 79;  // 256*79 >= 20000
    int base = t * CH;
    int local = 0;
    for (int i = 0; i < CH; ++i) {
        int idx = base + i;
        if (idx < N_NODES) local += deg[idx];
    }
    sums[t] = local;
    __syncthreads();
    for (int off = 1; off < 256; off <<= 1) {
        int v = (t >= off) ? sums[t - off] : 0;
        __syncthreads();
        sums[t] += v;
        __syncthreads();
    }
    int run = (t > 0) ? sums[t - 1] : 0;
    for (int i = 0; i < CH; ++i) {
        int idx = base + i;
        if (idx < N_NODES) {
            offsets[idx] = run;
            cursor[idx] = run;
            run += deg[idx];
        }
    }
}

__global__ __launch_bounds__(256) void csr_fill(
    const int* __restrict__ col, int* __restrict__ cursor,
    int* __restrict__ eid)
{
    int e = blockIdx.x * 256 + threadIdx.x;
    int pos = atomicAdd(&cursor[col[e]], 1);
    eid[pos] = e;
}

// ---------------- W fragment pre-pack ----------------
// wfrag[l][c][t][lane][j] = bf16( W[l][k][n] ), k = c*32 + (lane>>4)*8 + j,
// n = t*16 + (lane&15); zero outside 300x300.
__global__ __launch_bounds__(64) void wfrag_build(
    const float* __restrict__ W_convs, ushort_t* __restrict__ wfrag)
{
    const int c = blockIdx.x, t = blockIdx.y, l = blockIdx.z;
    const int lane = threadIdx.x;
    const int k0 = c * 32 + (lane >> 4) * 8;
    const int n  = t * 16 + (lane & 15);
    ushort_t* dst = wfrag + (size_t)l * WFRAG_USHORT_PER_LAYER
                  + ((size_t)(c * 19 + t) * 64 + lane) * 8;
    const float* Wl = W_convs + (size_t)l * HID * HID;
    #pragma unroll
    for (int j = 0; j < 8; ++j) {
        int k = k0 + j;
        float v = (k < HID && n < HID) ? Wl[(long)k * HID + n] : 0.f;
        dst[j] = f2bf(v);
    }
}

// ---------------- kernels ----------------

// K1: xW1[n][c] = b_init[c] + sum_k x[n][k] * W_init[k][c]   (k < 64)
__global__ __launch_bounds__(256) void node_init_gemm(
    const float* __restrict__ x, const float* __restrict__ W_init,
    const float* __restrict__ b_init, float* __restrict__ xW1)
{
    __shared__ float xs[16 * 64];
    const int tid = threadIdx.x;
    const long n0 = (long)blockIdx.x * 16;
    for (int i = tid; i < 16 * 64; i += 256) xs[i] = x[n0 * 64 + i];
    __syncthreads();
    const int nl = tid >> 4, ct = tid & 15;
    for (int q = 0; q < 19; ++q) {
        int c = ct + 16 * q;
        if (c < HID) {
            float acc = b_init[c];
            #pragma unroll 8
            for (int k = 0; k < 64; ++k)
                acc = fmaf(xs[nl * 64 + k], W_init[(long)k * HID + c], acc);
            xW1[(n0 + nl) * HID + c] = acc;
        }
    }
}

// K2: h[e][c] = relu(xW1[row[e]][c] + edge_attr[e] @ W2);  h stride HP, zero pad
__global__ __launch_bounds__(256) void h0_init(
    const float* __restrict__ edge_attr, const int* __restrict__ row,
    const float* __restrict__ xW1, const float* __restrict__ W_init,
    ushort_t* __restrict__ h)
{
    __shared__ float W2s[16 * HID];
    __shared__ float eas[16 * 16];
    const int tid = threadIdx.x;
    const long e0 = (long)blockIdx.x * 16;
    for (int i = tid; i < 16 * HID; i += 256) {
        int k = i / HID, c = i % HID;
        W2s[i] = W_init[(long)(64 + k) * HID + c];
    }
    eas[tid] = edge_attr[e0 * 16 + tid];
    __syncthreads();
    const int el = tid >> 4, ct = tid & 15;
    const long e = e0 + el;
    const int r = row[e];
    float ea[16];
    #pragma unroll
    for (int k = 0; k < 16; ++k) ea[k] = eas[el * 16 + k];
    for (int q = 0; q < 20; ++q) {
        int c = ct + 16 * q;   // 0..319
        if (c < HID) {
            float acc = xW1[(long)r * HID + c];
            #pragma unroll
            for (int k = 0; k < 16; ++k)
                acc = fmaf(ea[k], W2s[k * HID + c], acc);
            acc = fmaxf(acc, 0.f);
            h[e * HP + c] = f2bf(acc);
        } else {
            h[e * HP + c] = 0;   // zero pad cols 300..319 (gemm K-padding invariant)
        }
    }
}

// K3: IN-PLACE MFMA gemm  h <- h @ W  (E x 300 @ 300 x 300, padded 320/304).
// Block: 64 edges x 304 cols, 4 waves; wave w owns n-tiles [5w,5w+5) x 4 m-tiles.
// A-frags read directly from global (16B/lane); W staged per-32-k-chunk from
// pre-packed fragment-ordered wfrag (conflict-free ds_read_b128).
// In-place safety: __syncthreads() after k-loop => all A reads drain before any
// C store; cols 300..319 never written => zero-pad invariant preserved.
__global__ __launch_bounds__(256) void gemm_mfma(
    const ushort_t* A, const ushort_t* __restrict__ wfrag_l, ushort_t* C)
{
    __shared__ ushort_t Wc[WCHUNK_USHORT];  // 19456 B
    const int tid = threadIdx.x;
    const int wave = tid >> 6, lane = tid & 63;
    const int quad = lane >> 4, m = lane & 15;
    const long e0 = (long)blockIdx.x * 64;
    const int nt0 = wave * 5;
    const int NT = (wave == 3) ? 4 : 5;

    f32x4 acc[5][4];
    #pragma unroll
    for (int t = 0; t < 5; ++t)
        #pragma unroll
        for (int mt = 0; mt < 4; ++mt)
            acc[t][mt] = (f32x4){0.f, 0.f, 0.f, 0.f};

    for (int c = 0; c < 10; ++c) {
        __syncthreads();  // prev chunk's B reads done
        {
            const uint4* src = ((const uint4*)wfrag_l) + (size_t)c * (WCHUNK_USHORT / 8);
            uint4* dst = (uint4*)Wc;
            for (int i = tid; i < WCHUNK_USHORT / 8; i += 256) dst[i] = src[i];
        }
        __syncthreads();

        short8 a[4];
        #pragma unroll
        for (int mt = 0; mt < 4; ++mt) {
            const ushort_t* ap = A + (e0 + mt * 16 + m) * HP + c * 32 + quad * 8;
            a[mt] = *(const short8*)ap;
        }
        for (int t = 0; t < NT; ++t) {
            short8 b = *(const short8*)&Wc[((nt0 + t) * 64 + lane) * 8];
            #pragma unroll
            for (int mt = 0; mt < 4; ++mt)
                acc[t][mt] = __builtin_amdgcn_mfma_f32_16x16x32_bf16(
                    a[mt], b, acc[t][mt], 0, 0, 0);
        }
    }
    __syncthreads();  // all A reads complete before in-place stores

    for (int t = 0; t < NT; ++t) {
        int col = (nt0 + t) * 16 + m;
        if (col >= HID) continue;   // cols 300..303 are zero anyway
        #pragma unroll
        for (int mt = 0; mt < 4; ++mt) {
            long rbase = (e0 + mt * 16 + quad * 4) * HP + col;
            #pragma unroll
            for (int r = 0; r < 4; ++r)
                C[rbase + (long)r * HP] = f2bf(acc[t][mt][r]);
        }
    }
}

// K4: S[n][:] = sum over CSR edges of src[eid][:]   (no atomics)
__global__ __launch_bounds__(256) void gather_sum(
    const ushort_t* __restrict__ src, const int* __restrict__ offsets,
    const int* __restrict__ ends, const int* __restrict__ eid,
    float* __restrict__ S)
{
    long idx = (long)blockIdx.x * 256 + threadIdx.x;
    if (idx >= (long)N_NODES * 75) return;
    int n = (int)(idx / 75);
    int g = (int)(idx % 75);
    int beg = offsets[n], end = ends[n];
    float a0 = 0.f, a1 = 0.f, a2 = 0.f, a3 = 0.f;
    for (int j = beg; j < end; ++j) {
        int e = eid[j];
        ushort4 v = ((const ushort4*)src)[(long)e * (HP / 4) + g];
        a0 += bf2f(v.x); a1 += bf2f(v.y); a2 += bf2f(v.z); a3 += bf2f(v.w);
    }
    float4 o = {a0, a1, a2, a3};
    *(float4*)&S[(long)n * HID + 4 * g] = o;
}

// K5: tiled IN-PLACE edge update (pairs 2i,2i+1 never cross a 64-edge tile)
__global__ __launch_bounds__(256) void edge_update_tiled(
    ushort_t* h, const float* __restrict__ S,
    const float* __restrict__ xW1, const float* __restrict__ edge_attr,
    const float* __restrict__ W2, const float* __restrict__ bias,
    const int* __restrict__ row)
{
    __shared__ ushort_t hWs[64 * HP];   // 40960 B
    __shared__ float eas[64 * 16];
    __shared__ int rows[64];
    const int tid = threadIdx.x;
    const long e0 = (long)blockIdx.x * 64;

    for (int i = tid; i < 64 * (HP / 4); i += 256)
        ((ushort4*)hWs)[i] = ((const ushort4*)h)[e0 * (HP / 4) + i];
    for (int i = tid; i < 64 * 16; i += 256)
        eas[i] = edge_attr[e0 * 16 + i];
    if (tid < 64) rows[tid] = row[e0 + tid];
    __syncthreads();

    for (int i = tid; i < 64 * 75; i += 256) {
        int e = i / 75, g = i % 75;
        int c0 = 4 * g;
        long E = e0 + e;
        int r = rows[e];
        ushort4 wv = *(const ushort4*)&hWs[(e ^ 1) * HP + c0];
        float4 sv = *(const float4*)&S[(long)r * HID + c0];
        float4 bv = *(const float4*)&bias[c0];
        float4 xv = *(const float4*)&xW1[(long)r * HID + c0];
        float h0r[4] = {xv.x, xv.y, xv.z, xv.w};
        #pragma unroll
        for (int k = 0; k < 16; ++k) {
            float a = eas[e * 16 + k];
            const float4 w = *(const float4*)&W2[(long)k * HID + c0];
            h0r[0] = fmaf(a, w.x, h0r[0]);
            h0r[1] = fmaf(a, w.y, h0r[1]);
            h0r[2] = fmaf(a, w.z, h0r[2]);
            h0r[3] = fmaf(a, w.w, h0r[3]);
        }
        float o0 = fmaxf(sv.x - bf2f(wv.x) + bv.x + fmaxf(h0r[0], 0.f), 0.f);
        float o1 = fmaxf(sv.y - bf2f(wv.y) + bv.y + fmaxf(h0r[1], 0.f), 0.f);
        float o2 = fmaxf(sv.z - bf2f(wv.z) + bv.z + fmaxf(h0r[2], 0.f), 0.f);
        float o3 = fmaxf(sv.w - bf2f(wv.w) + bv.w + fmaxf(h0r[3], 0.f), 0.f);
        ushort4 ov;
        ov.x = f2bf(o0); ov.y = f2bf(o1); ov.z = f2bf(o2); ov.w = f2bf(o3);
        ((ushort4*)h)[E * (HP / 4) + g] = ov;
    }
    // keep zero-pad invariant for cols 300..319
    for (int i = tid; i < 64 * 5; i += 256) {
        int e = i / 5, g = 75 + i % 5;
        ushort4 z = {0, 0, 0, 0};
        ((ushort4*)h)[(e0 + e) * (HP / 4) + g] = z;
    }
}

// K7: hn[n] = relu(cat(x[n],S[n]) @ W_e2n + b); atomic pool into pooled[batch[n]]
__global__ __launch_bounds__(256) void e2n_pool(
    const float* __restrict__ x, const float* __restrict__ S,
    const float* __restrict__ W, const float* __restrict__ b,
    const int* __restrict__ batch, float* __restrict__ pooled)
{
    __shared__ float xs[16 * 64];
    __shared__ float Ss[16 * HID];
    const int tid = threadIdx.x;
    const long n0 = (long)blockIdx.x * 16;
    for (int i = tid; i < 16 * 64; i += 256) xs[i] = x[n0 * 64 + i];
    for (int i = tid; i < 16 * HID; i += 256) Ss[i] = S[n0 * HID + i];
    __syncthreads();
    const int nl = tid >> 4, ct = tid & 15;
    const long n = n0 + nl;
    const int gidx = batch[n];
    for (int q = 0; q < 19; ++q) {
        int c = ct + 16 * q;
        if (c < HID) {
            float acc = b[c];
            #pragma unroll 8
            for (int k = 0; k < 64; ++k)
                acc = fmaf(xs[nl * 64 + k], W[(long)k * HID + c], acc);
            #pragma unroll 4
            for (int k = 0; k < HID; ++k)
                acc = fmaf(Ss[nl * HID + k], W[(long)(64 + k) * HID + c], acc);
            acc = fmaxf(acc, 0.f);
            atomicAdd(&pooled[(long)gidx * HID + c], acc);
        }
    }
}

// K8: out[g] = pooled[g] @ W_ffn + b_ffn
__global__ __launch_bounds__(64) void ffn_out(
    const float* __restrict__ pooled, const float* __restrict__ W_ffn,
    const float* __restrict__ b_ffn, float* __restrict__ out)
{
    int g = blockIdx.x;
    int lane = threadIdx.x;
    float s = 0.f;
    for (int c = lane; c < HID; c += 64)
        s += pooled[(long)g * HID + c] * W_ffn[c];
    #pragma unroll
    for (int off = 32; off > 0; off >>= 1)
        s += __shfl_down(s, off, 64);
    if (lane == 0) out[g] = s + b_ffn[0];
}

extern "C" void kernel_launch(void* const* d_in, const int* in_sizes, int n_in,
                              void* d_out, int out_size, void* d_ws, size_t ws_size,
                              hipStream_t stream) {
    const float* x         = (const float*)d_in[0];
    const float* edge_attr = (const float*)d_in[1];
    const int*   edge_index= (const int*)d_in[2];
    const int*   batch     = (const int*)d_in[3];
    const float* W_init    = (const float*)d_in[4];
    const float* b_init    = (const float*)d_in[5];
    const float* W_convs   = (const float*)d_in[6];
    const float* b_convs   = (const float*)d_in[7];
    const float* W_e2n     = (const float*)d_in[8];
    const float* b_e2n     = (const float*)d_in[9];
    const float* W_ffn     = (const float*)d_in[10];
    const float* b_ffn     = (const float*)d_in[11];
    float* out = (float*)d_out;

    const int* row = edge_index;
    const int* col = edge_index + N_EDGES;
    const float* W2 = W_init + (size_t)F_NODE * HID;

    // Workspace (~255.0 MB): h 204.8M | S 24M | xW1 24M | pooled 153K
    // | cursor/offsets 160K | eid 1.28M | wfrag 584K
    const size_t need = (size_t)N_EDGES * HP * 2 + (size_t)N_NODES * HID * 4 * 2
                      + (size_t)N_GRAPHS * HID * 4 + (size_t)N_NODES * 4 * 2
                      + (size_t)N_EDGES * 4 + (size_t)DEPTH * WFRAG_USHORT_PER_LAYER * 2
                      + 8192;
    if (ws_size < need) return;  // clean absmax fail, not a crash

    char* p = (char*)d_ws;
    auto take = [&](size_t bytes) {
        char* q = p;
        p += (bytes + 255) & ~(size_t)255;
        return q;
    };
    ushort_t* h       = (ushort_t*)take((size_t)N_EDGES * HP * 2);
    float*    S       = (float*)take((size_t)N_NODES * HID * 4);
    float*    xW1     = (float*)take((size_t)N_NODES * HID * 4);
    float*    pooled  = (float*)take((size_t)N_GRAPHS * HID * 4);
    int*      cursor  = (int*)take((size_t)N_NODES * 4);
    int*      offsets = (int*)take((size_t)N_NODES * 4);
    int*      eid     = (int*)take((size_t)N_EDGES * 4);
    ushort_t* wfrag   = (ushort_t*)take((size_t)DEPTH * WFRAG_USHORT_PER_LAYER * 2);

    // CSR build
    hipMemsetAsync(cursor, 0, (size_t)N_NODES * 4, stream);
    csr_hist<<<N_EDGES / 256, 256, 0, stream>>>(col, cursor);
    csr_scan<<<1, 256, 0, stream>>>(cursor, offsets, cursor);
    csr_fill<<<N_EDGES / 256, 256, 0, stream>>>(col, cursor, eid);

    // W fragment pre-pack
    wfrag_build<<<dim3(10, 19, DEPTH), 64, 0, stream>>>(W_convs, wfrag);

    node_init_gemm<<<N_NODES / 16, 256, 0, stream>>>(x, W_init, b_init, xW1);
    h0_init<<<N_EDGES / 16, 256, 0, stream>>>(edge_attr, row, xW1, W_init, h);

    const int GS_GRID = ((N_NODES * 75) + 255) / 256;
    for (int l = 0; l < DEPTH; ++l) {
        gemm_mfma<<<N_EDGES / 64, 256, 0, stream>>>(
            h, wfrag + (size_t)l * WFRAG_USHORT_PER_LAYER, h);
        gather_sum<<<GS_GRID, 256, 0, stream>>>(h, offsets, cursor, eid, S);
        edge_update_tiled<<<N_EDGES / 64, 256, 0, stream>>>(
            h, S, xW1, edge_attr, W2, b_convs + l * HID, row);
    }

    gather_sum<<<GS_GRID, 256, 0, stream>>>(h, offsets, cursor, eid, S);
    hipMemsetAsync(pooled, 0, (size_t)N_GRAPHS * HID * 4, stream);
    e2n_pool<<<N_NODES / 16, 256, 0, stream>>>(x, S, W_e2n, b_e2n, batch, pooled);
    ffn_out<<<N_GRAPHS, 64, 0, stream>>>(pooled, W_ffn, b_ffn, out);
}

// Round 5
// 2891.970 us; speedup vs baseline: 2.4808x; 2.4808x over previous
//
#include <hip/hip_runtime.h>
#include <hip/hip_bf16.h>

typedef unsigned short ushort_t;
typedef __attribute__((ext_vector_type(8))) short short8;   // 8 bf16 = 4 VGPRs
typedef __attribute__((ext_vector_type(4))) float f32x4;    // MFMA C/D

#define N_NODES 20000
#define N_EDGES 320000
#define F_NODE 64
#define F_EDGE 16
#define HID 300
#define HP 320          // padded hidden: K-dim and row stride of h; 10 chunks of 32
#define NTILES 20       // padded N = 320 = 20 n-tiles of 16; 5 per wave (uniform!)
#define DEPTH 3
#define N_GRAPHS 128

#define WFRAG_USHORT_PER_LAYER (10 * NTILES * 64 * 8)  // 102400 ushorts = 204800 B
#define WCHUNK_USHORT (NTILES * 64 * 8)                // 10240 ushorts  = 20480 B

__device__ __forceinline__ float bf2f(ushort_t u) {
    union { unsigned int i; float f; } v;
    v.i = ((unsigned int)u) << 16;
    return v.f;
}
__device__ __forceinline__ ushort_t f2bf(float f) {
    union { float f; unsigned int i; } v;
    v.f = f;
    unsigned int x = v.i;
    unsigned int r = x + 0x7fffu + ((x >> 16) & 1u);  // RNE
    return (ushort_t)(r >> 16);
}

// ---------------- CSR build (col -> node adjacency) ----------------
__global__ __launch_bounds__(256) void csr_hist(
    const int* __restrict__ col, int* __restrict__ deg)
{
    int e = blockIdx.x * 256 + threadIdx.x;
    atomicAdd(&deg[col[e]], 1);
}

__global__ __launch_bounds__(256) void csr_scan(
    const int* __restrict__ deg, int* __restrict__ offsets,
    int* __restrict__ cursor)
{
    __shared__ int sums[256];
    const int t = threadIdx.x;
    const int CH = 79;  // 256*79 >= 20000
    int base = t * CH;
    int local = 0;
    for (int i = 0; i < CH; ++i) {
        int idx = base + i;
        if (idx < N_NODES) local += deg[idx];
    }
    sums[t] = local;
    __syncthreads();
    for (int off = 1; off < 256; off <<= 1) {
        int v = (t >= off) ? sums[t - off] : 0;
        __syncthreads();
        sums[t] += v;
        __syncthreads();
    }
    int run = (t > 0) ? sums[t - 1] : 0;
    for (int i = 0; i < CH; ++i) {
        int idx = base + i;
        if (idx < N_NODES) {
            offsets[idx] = run;
            cursor[idx] = run;
            run += deg[idx];
        }
    }
}

__global__ __launch_bounds__(256) void csr_fill(
    const int* __restrict__ col, int* __restrict__ cursor,
    int* __restrict__ eid)
{
    int e = blockIdx.x * 256 + threadIdx.x;
    int pos = atomicAdd(&cursor[col[e]], 1);
    eid[pos] = e;
}

// ---------------- W fragment pre-pack ----------------
// wfrag[l][c][t][lane][j] = bf16( W[l][k][n] ), k = c*32 + (lane>>4)*8 + j,
// n = t*16 + (lane&15); zero outside 300x300.
__global__ __launch_bounds__(64) void wfrag_build(
    const float* __restrict__ W_convs, ushort_t* __restrict__ wfrag)
{
    const int c = blockIdx.x, t = blockIdx.y, l = blockIdx.z;
    const int lane = threadIdx.x;
    const int k0 = c * 32 + (lane >> 4) * 8;
    const int n  = t * 16 + (lane & 15);
    ushort_t* dst = wfrag + (size_t)l * WFRAG_USHORT_PER_LAYER
                  + ((size_t)(c * NTILES + t) * 64 + lane) * 8;
    const float* Wl = W_convs + (size_t)l * HID * HID;
    #pragma unroll
    for (int j = 0; j < 8; ++j) {
        int k = k0 + j;
        float v = (k < HID && n < HID) ? Wl[(long)k * HID + n] : 0.f;
        dst[j] = f2bf(v);
    }
}

// ---------------- kernels ----------------

// K1: xW1[n][c] = b_init[c] + sum_k x[n][k] * W_init[k][c]   (k < 64)
__global__ __launch_bounds__(256) void node_init_gemm(
    const float* __restrict__ x, const float* __restrict__ W_init,
    const float* __restrict__ b_init, float* __restrict__ xW1)
{
    __shared__ float xs[16 * 64];
    const int tid = threadIdx.x;
    const long n0 = (long)blockIdx.x * 16;
    for (int i = tid; i < 16 * 64; i += 256) xs[i] = x[n0 * 64 + i];
    __syncthreads();
    const int nl = tid >> 4, ct = tid & 15;
    for (int q = 0; q < 19; ++q) {
        int c = ct + 16 * q;
        if (c < HID) {
            float acc = b_init[c];
            #pragma unroll 8
            for (int k = 0; k < 64; ++k)
                acc = fmaf(xs[nl * 64 + k], W_init[(long)k * HID + c], acc);
            xW1[(n0 + nl) * HID + c] = acc;
        }
    }
}

// K2: h[e][c] = relu(xW1[row[e]][c] + edge_attr[e] @ W2);  h stride HP, zero pad
__global__ __launch_bounds__(256) void h0_init(
    const float* __restrict__ edge_attr, const int* __restrict__ row,
    const float* __restrict__ xW1, const float* __restrict__ W_init,
    ushort_t* __restrict__ h)
{
    __shared__ float W2s[16 * HID];
    __shared__ float eas[16 * 16];
    const int tid = threadIdx.x;
    const long e0 = (long)blockIdx.x * 16;
    for (int i = tid; i < 16 * HID; i += 256) {
        int k = i / HID, c = i % HID;
        W2s[i] = W_init[(long)(64 + k) * HID + c];
    }
    eas[tid] = edge_attr[e0 * 16 + tid];
    __syncthreads();
    const int el = tid >> 4, ct = tid & 15;
    const long e = e0 + el;
    const int r = row[e];
    float ea[16];
    #pragma unroll
    for (int k = 0; k < 16; ++k) ea[k] = eas[el * 16 + k];
    for (int q = 0; q < 20; ++q) {
        int c = ct + 16 * q;   // 0..319
        if (c < HID) {
            float acc = xW1[(long)r * HID + c];
            #pragma unroll
            for (int k = 0; k < 16; ++k)
                acc = fmaf(ea[k], W2s[k * HID + c], acc);
            acc = fmaxf(acc, 0.f);
            h[e * HP + c] = f2bf(acc);
        } else {
            h[e * HP + c] = 0;   // zero pad cols 300..319 (gemm K-padding invariant)
        }
    }
}

// K3: IN-PLACE MFMA gemm  h <- h @ W  (E x 300 @ 300 x 300, padded 320/320).
// Block: 64 edges x 320 cols, 4 waves; wave w owns n-tiles [5w,5w+5) x 4 m-tiles.
// NT is the COMPILE-TIME constant 5 for every wave -> acc[][] fully unrolled,
// lives in VGPRs/AGPRs (round-4 failure: runtime NT forced acc to scratch ->
// 4.4 GB spill writes/dispatch, VGPR_Count=32).
// A-frags read directly from global (16B/lane); W staged per-32-k-chunk from
// pre-packed fragment-ordered wfrag (conflict-free ds_read_b128).
// In-place safety: __syncthreads() after k-loop => all A reads drain before any
// C store; cols 300..319 never written => zero-pad invariant preserved.
__global__ __launch_bounds__(256) void gemm_mfma(
    const ushort_t* A, const ushort_t* __restrict__ wfrag_l, ushort_t* C)
{
    __shared__ ushort_t Wc[WCHUNK_USHORT];  // 20480 B
    const int tid = threadIdx.x;
    const int wave = tid >> 6, lane = tid & 63;
    const int quad = lane >> 4, m = lane & 15;
    const long e0 = (long)blockIdx.x * 64;
    const int nt0 = wave * 5;

    f32x4 acc[5][4];
    #pragma unroll
    for (int t = 0; t < 5; ++t)
        #pragma unroll
        for (int mt = 0; mt < 4; ++mt)
            acc[t][mt] = (f32x4){0.f, 0.f, 0.f, 0.f};

    for (int c = 0; c < 10; ++c) {
        __syncthreads();  // prev chunk's B reads done
        {
            const uint4* src = ((const uint4*)wfrag_l) + (size_t)c * (WCHUNK_USHORT / 8);
            uint4* dst = (uint4*)Wc;
            for (int i = tid; i < WCHUNK_USHORT / 8; i += 256) dst[i] = src[i];
        }
        __syncthreads();

        short8 a[4];
        #pragma unroll
        for (int mt = 0; mt < 4; ++mt) {
            const ushort_t* ap = A + (e0 + mt * 16 + m) * HP + c * 32 + quad * 8;
            a[mt] = *(const short8*)ap;
        }
        #pragma unroll
        for (int t = 0; t < 5; ++t) {
            short8 b = *(const short8*)&Wc[((nt0 + t) * 64 + lane) * 8];
            #pragma unroll
            for (int mt = 0; mt < 4; ++mt)
                acc[t][mt] = __builtin_amdgcn_mfma_f32_16x16x32_bf16(
                    a[mt], b, acc[t][mt], 0, 0, 0);
        }
    }
    __syncthreads();  // all A reads complete before in-place stores

    #pragma unroll
    for (int t = 0; t < 5; ++t) {
        int col = (nt0 + t) * 16 + m;
        if (col >= HID) continue;   // pad cols stay zero
        #pragma unroll
        for (int mt = 0; mt < 4; ++mt) {
            long rbase = (e0 + mt * 16 + quad * 4) * HP + col;
            #pragma unroll
            for (int r = 0; r < 4; ++r)
                C[rbase + (long)r * HP] = f2bf(acc[t][mt][r]);
        }
    }
}

// K4: S[n][:] = sum over CSR edges of src[eid][:]   (no atomics)
__global__ __launch_bounds__(256) void gather_sum(
    const ushort_t* __restrict__ src, const int* __restrict__ offsets,
    const int* __restrict__ ends, const int* __restrict__ eid,
    float* __restrict__ S)
{
    long idx = (long)blockIdx.x * 256 + threadIdx.x;
    if (idx >= (long)N_NODES * 75) return;
    int n = (int)(idx / 75);
    int g = (int)(idx % 75);
    int beg = offsets[n], end = ends[n];
    float a0 = 0.f, a1 = 0.f, a2 = 0.f, a3 = 0.f;
    for (int j = beg; j < end; ++j) {
        int e = eid[j];
        ushort4 v = ((const ushort4*)src)[(long)e * (HP / 4) + g];
        a0 += bf2f(v.x); a1 += bf2f(v.y); a2 += bf2f(v.z); a3 += bf2f(v.w);
    }
    float4 o = {a0, a1, a2, a3};
    *(float4*)&S[(long)n * HID + 4 * g] = o;
}

// K5: tiled IN-PLACE edge update (pairs 2i,2i+1 never cross a 64-edge tile)
__global__ __launch_bounds__(256) void edge_update_tiled(
    ushort_t* h, const float* __restrict__ S,
    const float* __restrict__ xW1, const float* __restrict__ edge_attr,
    const float* __restrict__ W2, const float* __restrict__ bias,
    const int* __restrict__ row)
{
    __shared__ ushort_t hWs[64 * HP];   // 40960 B
    __shared__ float eas[64 * 16];
    __shared__ int rows[64];
    const int tid = threadIdx.x;
    const long e0 = (long)blockIdx.x * 64;

    for (int i = tid; i < 64 * (HP / 4); i += 256)
        ((ushort4*)hWs)[i] = ((const ushort4*)h)[e0 * (HP / 4) + i];
    for (int i = tid; i < 64 * 16; i += 256)
        eas[i] = edge_attr[e0 * 16 + i];
    if (tid < 64) rows[tid] = row[e0 + tid];
    __syncthreads();

    for (int i = tid; i < 64 * 75; i += 256) {
        int e = i / 75, g = i % 75;
        int c0 = 4 * g;
        long E = e0 + e;
        int r = rows[e];
        ushort4 wv = *(const ushort4*)&hWs[(e ^ 1) * HP + c0];
        float4 sv = *(const float4*)&S[(long)r * HID + c0];
        float4 bv = *(const float4*)&bias[c0];
        float4 xv = *(const float4*)&xW1[(long)r * HID + c0];
        float h0r[4] = {xv.x, xv.y, xv.z, xv.w};
        #pragma unroll
        for (int k = 0; k < 16; ++k) {
            float a = eas[e * 16 + k];
            const float4 w = *(const float4*)&W2[(long)k * HID + c0];
            h0r[0] = fmaf(a, w.x, h0r[0]);
            h0r[1] = fmaf(a, w.y, h0r[1]);
            h0r[2] = fmaf(a, w.z, h0r[2]);
            h0r[3] = fmaf(a, w.w, h0r[3]);
        }
        float o0 = fmaxf(sv.x - bf2f(wv.x) + bv.x + fmaxf(h0r[0], 0.f), 0.f);
        float o1 = fmaxf(sv.y - bf2f(wv.y) + bv.y + fmaxf(h0r[1], 0.f), 0.f);
        float o2 = fmaxf(sv.z - bf2f(wv.z) + bv.z + fmaxf(h0r[2], 0.f), 0.f);
        float o3 = fmaxf(sv.w - bf2f(wv.w) + bv.w + fmaxf(h0r[3], 0.f), 0.f);
        ushort4 ov;
        ov.x = f2bf(o0); ov.y = f2bf(o1); ov.z = f2bf(o2); ov.w = f2bf(o3);
        ((ushort4*)h)[E * (HP / 4) + g] = ov;
    }
    // keep zero-pad invariant for cols 300..319
    for (int i = tid; i < 64 * 5; i += 256) {
        int e = i / 5, g = 75 + i % 5;
        ushort4 z = {0, 0, 0, 0};
        ((ushort4*)h)[(e0 + e) * (HP / 4) + g] = z;
    }
}

// K7: hn[n] = relu(cat(x[n],S[n]) @ W_e2n + b); atomic pool into pooled[batch[n]]
__global__ __launch_bounds__(256) void e2n_pool(
    const float* __restrict__ x, const float* __restrict__ S,
    const float* __restrict__ W, const float* __restrict__ b,
    const int* __restrict__ batch, float* __restrict__ pooled)
{
    __shared__ float xs[16 * 64];
    __shared__ float Ss[16 * HID];
    const int tid = threadIdx.x;
    const long n0 = (long)blockIdx.x * 16;
    for (int i = tid; i < 16 * 64; i += 256) xs[i] = x[n0 * 64 + i];
    for (int i = tid; i < 16 * HID; i += 256) Ss[i] = S[n0 * HID + i];
    __syncthreads();
    const int nl = tid >> 4, ct = tid & 15;
    const long n = n0 + nl;
    const int gidx = batch[n];
    for (int q = 0; q < 19; ++q) {
        int c = ct + 16 * q;
        if (c < HID) {
            float acc = b[c];
            #pragma unroll 8
            for (int k = 0; k < 64; ++k)
                acc = fmaf(xs[nl * 64 + k], W[(long)k * HID + c], acc);
            #pragma unroll 4
            for (int k = 0; k < HID; ++k)
                acc = fmaf(Ss[nl * HID + k], W[(long)(64 + k) * HID + c], acc);
            acc = fmaxf(acc, 0.f);
            atomicAdd(&pooled[(long)gidx * HID + c], acc);
        }
    }
}

// K8: out[g] = pooled[g] @ W_ffn + b_ffn
__global__ __launch_bounds__(64) void ffn_out(
    const float* __restrict__ pooled, const float* __restrict__ W_ffn,
    const float* __restrict__ b_ffn, float* __restrict__ out)
{
    int g = blockIdx.x;
    int lane = threadIdx.x;
    float s = 0.f;
    for (int c = lane; c < HID; c += 64)
        s += pooled[(long)g * HID + c] * W_ffn[c];
    #pragma unroll
    for (int off = 32; off > 0; off >>= 1)
        s += __shfl_down(s, off, 64);
    if (lane == 0) out[g] = s + b_ffn[0];
}

extern "C" void kernel_launch(void* const* d_in, const int* in_sizes, int n_in,
                              void* d_out, int out_size, void* d_ws, size_t ws_size,
                              hipStream_t stream) {
    const float* x         = (const float*)d_in[0];
    const float* edge_attr = (const float*)d_in[1];
    const int*   edge_index= (const int*)d_in[2];
    const int*   batch     = (const int*)d_in[3];
    const float* W_init    = (const float*)d_in[4];
    const float* b_init    = (const float*)d_in[5];
    const float* W_convs   = (const float*)d_in[6];
    const float* b_convs   = (const float*)d_in[7];
    const float* W_e2n     = (const float*)d_in[8];
    const float* b_e2n     = (const float*)d_in[9];
    const float* W_ffn     = (const float*)d_in[10];
    const float* b_ffn     = (const float*)d_in[11];
    float* out = (float*)d_out;

    const int* row = edge_index;
    const int* col = edge_index + N_EDGES;
    const float* W2 = W_init + (size_t)F_NODE * HID;

    // Workspace (~255 MB): h 204.8M | S 24M | xW1 24M | pooled 153K
    // | cursor/offsets 160K | eid 1.28M | wfrag 614K
    const size_t need = (size_t)N_EDGES * HP * 2 + (size_t)N_NODES * HID * 4 * 2
                      + (size_t)N_GRAPHS * HID * 4 + (size_t)N_NODES * 4 * 2
                      + (size_t)N_EDGES * 4 + (size_t)DEPTH * WFRAG_USHORT_PER_LAYER * 2
                      + 8192;
    if (ws_size < need) return;  // clean absmax fail, not a crash

    char* p = (char*)d_ws;
    auto take = [&](size_t bytes) {
        char* q = p;
        p += (bytes + 255) & ~(size_t)255;
        return q;
    };
    ushort_t* h       = (ushort_t*)take((size_t)N_EDGES * HP * 2);
    float*    S       = (float*)take((size_t)N_NODES * HID * 4);
    float*    xW1     = (float*)take((size_t)N_NODES * HID * 4);
    float*    pooled  = (float*)take((size_t)N_GRAPHS * HID * 4);
    int*      cursor  = (int*)take((size_t)N_NODES * 4);
    int*      offsets = (int*)take((size_t)N_NODES * 4);
    int*      eid     = (int*)take((size_t)N_EDGES * 4);
    ushort_t* wfrag   = (ushort_t*)take((size_t)DEPTH * WFRAG_USHORT_PER_LAYER * 2);

    // CSR build
    hipMemsetAsync(cursor, 0, (size_t)N_NODES * 4, stream);
    csr_hist<<<N_EDGES / 256, 256, 0, stream>>>(col, cursor);
    csr_scan<<<1, 256, 0, stream>>>(cursor, offsets, cursor);
    csr_fill<<<N_EDGES / 256, 256, 0, stream>>>(col, cursor, eid);

    // W fragment pre-pack
    wfrag_build<<<dim3(10, NTILES, DEPTH), 64, 0, stream>>>(W_convs, wfrag);

    node_init_gemm<<<N_NODES / 16, 256, 0, stream>>>(x, W_init, b_init, xW1);
    h0_init<<<N_EDGES / 16, 256, 0, stream>>>(edge_attr, row, xW1, W_init, h);

    const int GS_GRID = ((N_NODES * 75) + 255) / 256;
    for (int l = 0; l < DEPTH; ++l) {
        gemm_mfma<<<N_EDGES / 64, 256, 0, stream>>>(
            h, wfrag + (size_t)l * WFRAG_USHORT_PER_LAYER, h);
        gather_sum<<<GS_GRID, 256, 0, stream>>>(h, offsets, cursor, eid, S);
        edge_update_tiled<<<N_EDGES / 64, 256, 0, stream>>>(
            h, S, xW1, edge_attr, W2, b_convs + l * HID, row);
    }

    gather_sum<<<GS_GRID, 256, 0, stream>>>(h, offsets, cursor, eid, S);
    hipMemsetAsync(pooled, 0, (size_t)N_GRAPHS * HID * 4, stream);
    e2n_pool<<<N_NODES / 16, 256, 0, stream>>>(x, S, W_e2n, b_e2n, batch, pooled);
    ffn_out<<<N_GRAPHS, 64, 0, stream>>>(pooled, W_ffn, b_ffn, out);
}

// Round 6
// 2320.198 us; speedup vs baseline: 3.0922x; 1.2464x over previous
//
#include <hip/hip_runtime.h>
#include <hip/hip_bf16.h>

typedef unsigned short ushort_t;
typedef __attribute__((ext_vector_type(8))) short short8;   // 8 bf16 = 4 VGPRs
typedef __attribute__((ext_vector_type(4))) float f32x4;    // MFMA C/D

#define N_NODES 20000
#define N_EDGES 320000
#define F_NODE 64
#define F_EDGE 16
#define HID 300
#define HP 320          // padded hidden: K-dim and row stride of h; 10 chunks of 32
#define NTILES 20       // padded N = 320 = 20 n-tiles of 16; 5 per wave (uniform!)
#define DEPTH 3
#define N_GRAPHS 128
#define KE2N 384        // e2n K: 64 (x) + 300 (S) + 20 pad; 12 chunks of 32

#define WFRAG_USHORT_PER_LAYER (10 * NTILES * 64 * 8)  // 102400 ushorts
#define WCHUNK_USHORT (NTILES * 64 * 8)                // 10240 ushorts = 20480 B
#define W2FRAG_USHORT (12 * NTILES * 64 * 8)           // 122880 ushorts

__device__ __forceinline__ float bf2f(ushort_t u) {
    union { unsigned int i; float f; } v;
    v.i = ((unsigned int)u) << 16;
    return v.f;
}
__device__ __forceinline__ ushort_t f2bf(float f) {
    union { float f; unsigned int i; } v;
    v.f = f;
    unsigned int x = v.i;
    unsigned int r = x + 0x7fffu + ((x >> 16) & 1u);  // RNE
    return (ushort_t)(r >> 16);
}

// ---------------- CSR build (col -> node adjacency) ----------------
__global__ __launch_bounds__(256) void csr_hist(
    const int* __restrict__ col, int* __restrict__ deg)
{
    int e = blockIdx.x * 256 + threadIdx.x;
    atomicAdd(&deg[col[e]], 1);
}

__global__ __launch_bounds__(256) void csr_scan(
    const int* __restrict__ deg, int* __restrict__ offsets,
    int* __restrict__ cursor)
{
    __shared__ int sums[256];
    const int t = threadIdx.x;
    const int CH = 79;  // 256*79 >= 20000
    int base = t * CH;
    int local = 0;
    for (int i = 0; i < CH; ++i) {
        int idx = base + i;
        if (idx < N_NODES) local += deg[idx];
    }
    sums[t] = local;
    __syncthreads();
    for (int off = 1; off < 256; off <<= 1) {
        int v = (t >= off) ? sums[t - off] : 0;
        __syncthreads();
        sums[t] += v;
        __syncthreads();
    }
    int run = (t > 0) ? sums[t - 1] : 0;
    for (int i = 0; i < CH; ++i) {
        int idx = base + i;
        if (idx < N_NODES) {
            offsets[idx] = run;
            cursor[idx] = run;
            run += deg[idx];
        }
    }
}

__global__ __launch_bounds__(256) void csr_fill(
    const int* __restrict__ col, int* __restrict__ cursor,
    int* __restrict__ eid)
{
    int e = blockIdx.x * 256 + threadIdx.x;
    int pos = atomicAdd(&cursor[col[e]], 1);
    eid[pos] = e;
}

// graph histogram over sorted batch (bounds-checked grid)
__global__ __launch_bounds__(256) void ghist(
    const int* __restrict__ batch, int* __restrict__ gdeg)
{
    int n = blockIdx.x * 256 + threadIdx.x;
    if (n < N_NODES) atomicAdd(&gdeg[batch[n]], 1);
}

// single-block scan of gdeg[128] -> goff[129]
__global__ __launch_bounds__(128) void gscan(
    const int* __restrict__ gdeg, int* __restrict__ goff)
{
    __shared__ int s[128];
    int t = threadIdx.x;
    int d = gdeg[t];
    s[t] = d;
    __syncthreads();
    for (int off = 1; off < 128; off <<= 1) {
        int v = (t >= off) ? s[t - off] : 0;
        __syncthreads();
        s[t] += v;
        __syncthreads();
    }
    goff[t] = s[t] - d;
    if (t == 127) goff[128] = s[127];
}

// ---------------- W fragment pre-pack ----------------
__global__ __launch_bounds__(64) void wfrag_build(
    const float* __restrict__ W_convs, ushort_t* __restrict__ wfrag)
{
    const int c = blockIdx.x, t = blockIdx.y, l = blockIdx.z;
    const int lane = threadIdx.x;
    const int k0 = c * 32 + (lane >> 4) * 8;
    const int n  = t * 16 + (lane & 15);
    ushort_t* dst = wfrag + (size_t)l * WFRAG_USHORT_PER_LAYER
                  + ((size_t)(c * NTILES + t) * 64 + lane) * 8;
    const float* Wl = W_convs + (size_t)l * HID * HID;
    #pragma unroll
    for (int j = 0; j < 8; ++j) {
        int k = k0 + j;
        float v = (k < HID && n < HID) ? Wl[(long)k * HID + n] : 0.f;
        dst[j] = f2bf(v);
    }
}

// W_e2n fragments: K=364 (pad 384), N=300 (pad 320)
__global__ __launch_bounds__(64) void wfrag2_build(
    const float* __restrict__ W_e2n, ushort_t* __restrict__ wfrag2)
{
    const int c = blockIdx.x, t = blockIdx.y;
    const int lane = threadIdx.x;
    const int k0 = c * 32 + (lane >> 4) * 8;
    const int n  = t * 16 + (lane & 15);
    ushort_t* dst = wfrag2 + ((size_t)(c * NTILES + t) * 64 + lane) * 8;
    #pragma unroll
    for (int j = 0; j < 8; ++j) {
        int k = k0 + j;
        float v = (k < F_NODE + HID && n < HID) ? W_e2n[(long)k * HID + n] : 0.f;
        dst[j] = f2bf(v);
    }
}

// ---------------- kernels ----------------

// K1: xW1[n][c] = b_init[c] + sum_k x[n][k] * W_init[k][c]   (k < 64)
__global__ __launch_bounds__(256) void node_init_gemm(
    const float* __restrict__ x, const float* __restrict__ W_init,
    const float* __restrict__ b_init, float* __restrict__ xW1)
{
    __shared__ float xs[16 * 64];
    const int tid = threadIdx.x;
    const long n0 = (long)blockIdx.x * 16;
    for (int i = tid; i < 16 * 64; i += 256) xs[i] = x[n0 * 64 + i];
    __syncthreads();
    const int nl = tid >> 4, ct = tid & 15;
    for (int q = 0; q < 19; ++q) {
        int c = ct + 16 * q;
        if (c < HID) {
            float acc = b_init[c];
            #pragma unroll 8
            for (int k = 0; k < 64; ++k)
                acc = fmaf(xs[nl * 64 + k], W_init[(long)k * HID + c], acc);
            xW1[(n0 + nl) * HID + c] = acc;
        }
    }
}

// K2: h[e][c] = relu(xW1[row[e]][c] + edge_attr[e] @ W2);  h stride HP, zero pad
__global__ __launch_bounds__(256) void h0_init(
    const float* __restrict__ edge_attr, const int* __restrict__ row,
    const float* __restrict__ xW1, const float* __restrict__ W_init,
    ushort_t* __restrict__ h)
{
    __shared__ float W2s[16 * HID];
    __shared__ float eas[16 * 16];
    const int tid = threadIdx.x;
    const long e0 = (long)blockIdx.x * 16;
    for (int i = tid; i < 16 * HID; i += 256) {
        int k = i / HID, c = i % HID;
        W2s[i] = W_init[(long)(64 + k) * HID + c];
    }
    eas[tid] = edge_attr[e0 * 16 + tid];
    __syncthreads();
    const int el = tid >> 4, ct = tid & 15;
    const long e = e0 + el;
    const int r = row[e];
    float ea[16];
    #pragma unroll
    for (int k = 0; k < 16; ++k) ea[k] = eas[el * 16 + k];
    for (int q = 0; q < 20; ++q) {
        int c = ct + 16 * q;
        if (c < HID) {
            float acc = xW1[(long)r * HID + c];
            #pragma unroll
            for (int k = 0; k < 16; ++k)
                acc = fmaf(ea[k], W2s[k * HID + c], acc);
            acc = fmaxf(acc, 0.f);
            h[e * HP + c] = f2bf(acc);
        } else {
            h[e * HP + c] = 0;
        }
    }
}

// K3: IN-PLACE MFMA gemm  h <- h @ W  (uniform 5 n-tiles/wave; acc in regs)
__global__ __launch_bounds__(256) void gemm_mfma(
    const ushort_t* A, const ushort_t* __restrict__ wfrag_l, ushort_t* C)
{
    __shared__ ushort_t Wc[WCHUNK_USHORT];
    const int tid = threadIdx.x;
    const int wave = tid >> 6, lane = tid & 63;
    const int quad = lane >> 4, m = lane & 15;
    const long e0 = (long)blockIdx.x * 64;
    const int nt0 = wave * 5;

    f32x4 acc[5][4];
    #pragma unroll
    for (int t = 0; t < 5; ++t)
        #pragma unroll
        for (int mt = 0; mt < 4; ++mt)
            acc[t][mt] = (f32x4){0.f, 0.f, 0.f, 0.f};

    for (int c = 0; c < 10; ++c) {
        __syncthreads();
        {
            const uint4* src = ((const uint4*)wfrag_l) + (size_t)c * (WCHUNK_USHORT / 8);
            uint4* dst = (uint4*)Wc;
            for (int i = tid; i < WCHUNK_USHORT / 8; i += 256) dst[i] = src[i];
        }
        __syncthreads();

        short8 a[4];
        #pragma unroll
        for (int mt = 0; mt < 4; ++mt) {
            const ushort_t* ap = A + (e0 + mt * 16 + m) * HP + c * 32 + quad * 8;
            a[mt] = *(const short8*)ap;
        }
        #pragma unroll
        for (int t = 0; t < 5; ++t) {
            short8 b = *(const short8*)&Wc[((nt0 + t) * 64 + lane) * 8];
            #pragma unroll
            for (int mt = 0; mt < 4; ++mt)
                acc[t][mt] = __builtin_amdgcn_mfma_f32_16x16x32_bf16(
                    a[mt], b, acc[t][mt], 0, 0, 0);
        }
    }
    __syncthreads();

    #pragma unroll
    for (int t = 0; t < 5; ++t) {
        int col = (nt0 + t) * 16 + m;
        if (col >= HID) continue;
        #pragma unroll
        for (int mt = 0; mt < 4; ++mt) {
            long rbase = (e0 + mt * 16 + quad * 4) * HP + col;
            #pragma unroll
            for (int r = 0; r < 4; ++r)
                C[rbase + (long)r * HP] = f2bf(acc[t][mt][r]);
        }
    }
}

// K4: S[n][:] = sum over CSR edges of src[eid][:]   (fp32 out, 2-way ILP)
__global__ __launch_bounds__(256) void gather_sum(
    const ushort_t* __restrict__ src, const int* __restrict__ offsets,
    const int* __restrict__ ends, const int* __restrict__ eid,
    float* __restrict__ S)
{
    long idx = (long)blockIdx.x * 256 + threadIdx.x;
    if (idx >= (long)N_NODES * 75) return;
    int n = (int)(idx / 75);
    int g = (int)(idx % 75);
    int beg = offsets[n], end = ends[n];
    float a0 = 0.f, a1 = 0.f, a2 = 0.f, a3 = 0.f;
    float b0 = 0.f, b1 = 0.f, b2 = 0.f, b3 = 0.f;
    int j = beg;
    for (; j + 1 < end; j += 2) {
        int e0i = eid[j], e1i = eid[j + 1];
        ushort4 v0 = ((const ushort4*)src)[(long)e0i * (HP / 4) + g];
        ushort4 v1 = ((const ushort4*)src)[(long)e1i * (HP / 4) + g];
        a0 += bf2f(v0.x); a1 += bf2f(v0.y); a2 += bf2f(v0.z); a3 += bf2f(v0.w);
        b0 += bf2f(v1.x); b1 += bf2f(v1.y); b2 += bf2f(v1.z); b3 += bf2f(v1.w);
    }
    if (j < end) {
        int e0i = eid[j];
        ushort4 v0 = ((const ushort4*)src)[(long)e0i * (HP / 4) + g];
        a0 += bf2f(v0.x); a1 += bf2f(v0.y); a2 += bf2f(v0.z); a3 += bf2f(v0.w);
    }
    float4 o = {a0 + b0, a1 + b1, a2 + b2, a3 + b3};
    *(float4*)&S[(long)n * HID + 4 * g] = o;
}

// K4b: final gather -> bf16 directly into Ab cols 64..363 (stride KE2N)
__global__ __launch_bounds__(256) void gather_ab(
    const ushort_t* __restrict__ src, const int* __restrict__ offsets,
    const int* __restrict__ ends, const int* __restrict__ eid,
    ushort_t* __restrict__ Ab)
{
    long idx = (long)blockIdx.x * 256 + threadIdx.x;
    if (idx >= (long)N_NODES * 75) return;
    int n = (int)(idx / 75);
    int g = (int)(idx % 75);
    int beg = offsets[n], end = ends[n];
    float a0 = 0.f, a1 = 0.f, a2 = 0.f, a3 = 0.f;
    float b0 = 0.f, b1 = 0.f, b2 = 0.f, b3 = 0.f;
    int j = beg;
    for (; j + 1 < end; j += 2) {
        int e0i = eid[j], e1i = eid[j + 1];
        ushort4 v0 = ((const ushort4*)src)[(long)e0i * (HP / 4) + g];
        ushort4 v1 = ((const ushort4*)src)[(long)e1i * (HP / 4) + g];
        a0 += bf2f(v0.x); a1 += bf2f(v0.y); a2 += bf2f(v0.z); a3 += bf2f(v0.w);
        b0 += bf2f(v1.x); b1 += bf2f(v1.y); b2 += bf2f(v1.z); b3 += bf2f(v1.w);
    }
    if (j < end) {
        int e0i = eid[j];
        ushort4 v0 = ((const ushort4*)src)[(long)e0i * (HP / 4) + g];
        a0 += bf2f(v0.x); a1 += bf2f(v0.y); a2 += bf2f(v0.z); a3 += bf2f(v0.w);
    }
    ushort4 o;
    o.x = f2bf(a0 + b0); o.y = f2bf(a1 + b1);
    o.z = f2bf(a2 + b2); o.w = f2bf(a3 + b3);
    *(ushort4*)&Ab[(long)n * KE2N + 64 + 4 * g] = o;
}

// fill Ab cols 0..63 from x (bf16) and zero cols 364..383
__global__ __launch_bounds__(256) void x_fill(
    const float* __restrict__ x, ushort_t* __restrict__ Ab)
{
    long idx = (long)blockIdx.x * 256 + threadIdx.x;  // over N_NODES*21
    if (idx >= (long)N_NODES * 21) return;
    int n = (int)(idx / 21);
    int q = (int)(idx % 21);
    ushort4 o;
    if (q < 16) {
        float4 v = *(const float4*)&x[(long)n * 64 + 4 * q];
        o.x = f2bf(v.x); o.y = f2bf(v.y); o.z = f2bf(v.z); o.w = f2bf(v.w);
        *(ushort4*)&Ab[(long)n * KE2N + 4 * q] = o;
    } else {
        o.x = 0; o.y = 0; o.z = 0; o.w = 0;
        *(ushort4*)&Ab[(long)n * KE2N + 364 + 4 * (q - 16)] = o;
    }
}

// K7: hn = relu(Ab @ W_e2n + b)  via MFMA; hn fp32 [N_NODES][HP]
__global__ __launch_bounds__(256) void e2n_mfma(
    const ushort_t* __restrict__ Ab, const ushort_t* __restrict__ wfrag2,
    const float* __restrict__ b_e2n, float* __restrict__ hn)
{
    __shared__ ushort_t Wc[WCHUNK_USHORT];
    const int tid = threadIdx.x;
    const int wave = tid >> 6, lane = tid & 63;
    const int quad = lane >> 4, m = lane & 15;
    const long n0 = (long)blockIdx.x * 64;
    const int nt0 = wave * 5;

    f32x4 acc[5][4];
    #pragma unroll
    for (int t = 0; t < 5; ++t)
        #pragma unroll
        for (int mt = 0; mt < 4; ++mt)
            acc[t][mt] = (f32x4){0.f, 0.f, 0.f, 0.f};

    for (int c = 0; c < 12; ++c) {
        __syncthreads();
        {
            const uint4* src = ((const uint4*)wfrag2) + (size_t)c * (WCHUNK_USHORT / 8);
            uint4* dst = (uint4*)Wc;
            for (int i = tid; i < WCHUNK_USHORT / 8; i += 256) dst[i] = src[i];
        }
        __syncthreads();

        short8 a[4];
        #pragma unroll
        for (int mt = 0; mt < 4; ++mt) {
            long r = n0 + mt * 16 + m;
            if (r > N_NODES - 1) r = N_NODES - 1;  // clamp (stores masked)
            a[mt] = *(const short8*)(Ab + r * KE2N + c * 32 + quad * 8);
        }
        #pragma unroll
        for (int t = 0; t < 5; ++t) {
            short8 b = *(const short8*)&Wc[((nt0 + t) * 64 + lane) * 8];
            #pragma unroll
            for (int mt = 0; mt < 4; ++mt)
                acc[t][mt] = __builtin_amdgcn_mfma_f32_16x16x32_bf16(
                    a[mt], b, acc[t][mt], 0, 0, 0);
        }
    }

    #pragma unroll
    for (int t = 0; t < 5; ++t) {
        int col = (nt0 + t) * 16 + m;
        if (col >= HID) continue;
        float bias = b_e2n[col];
        #pragma unroll
        for (int mt = 0; mt < 4; ++mt) {
            long rw = n0 + mt * 16 + quad * 4;
            #pragma unroll
            for (int r = 0; r < 4; ++r) {
                long rowi = rw + r;
                if (rowi < N_NODES)
                    hn[rowi * HP + col] = fmaxf(acc[t][mt][r] + bias, 0.f);
            }
        }
    }
}

// K7b: pooled[g][c] = sum of hn rows in [goff[g], goff[g+1])  (sorted batch)
__global__ __launch_bounds__(256) void pool_graph(
    const float* __restrict__ hn, const int* __restrict__ goff,
    float* __restrict__ pooled)
{
    int g = blockIdx.x;
    int beg = goff[g], end = goff[g + 1];
    for (int c = threadIdx.x; c < HID; c += 256) {
        float acc = 0.f;
        for (int n = beg; n < end; ++n)
            acc += hn[(long)n * HP + c];
        pooled[(long)g * HID + c] = acc;
    }
}

// K5: tiled IN-PLACE edge update (pairs 2i,2i+1 never cross a 64-edge tile)
__global__ __launch_bounds__(256) void edge_update_tiled(
    ushort_t* h, const float* __restrict__ S,
    const float* __restrict__ xW1, const float* __restrict__ edge_attr,
    const float* __restrict__ W2, const float* __restrict__ bias,
    const int* __restrict__ row)
{
    __shared__ ushort_t hWs[64 * HP];
    __shared__ float eas[64 * 16];
    __shared__ int rows[64];
    const int tid = threadIdx.x;
    const long e0 = (long)blockIdx.x * 64;

    for (int i = tid; i < 64 * (HP / 4); i += 256)
        ((ushort4*)hWs)[i] = ((const ushort4*)h)[e0 * (HP / 4) + i];
    for (int i = tid; i < 64 * 16; i += 256)
        eas[i] = edge_attr[e0 * 16 + i];
    if (tid < 64) rows[tid] = row[e0 + tid];
    __syncthreads();

    for (int i = tid; i < 64 * 75; i += 256) {
        int e = i / 75, g = i % 75;
        int c0 = 4 * g;
        long E = e0 + e;
        int r = rows[e];
        ushort4 wv = *(const ushort4*)&hWs[(e ^ 1) * HP + c0];
        float4 sv = *(const float4*)&S[(long)r * HID + c0];
        float4 bv = *(const float4*)&bias[c0];
        float4 xv = *(const float4*)&xW1[(long)r * HID + c0];
        float h0r[4] = {xv.x, xv.y, xv.z, xv.w};
        #pragma unroll
        for (int k = 0; k < 16; ++k) {
            float a = eas[e * 16 + k];
            const float4 w = *(const float4*)&W2[(long)k * HID + c0];
            h0r[0] = fmaf(a, w.x, h0r[0]);
            h0r[1] = fmaf(a, w.y, h0r[1]);
            h0r[2] = fmaf(a, w.z, h0r[2]);
            h0r[3] = fmaf(a, w.w, h0r[3]);
        }
        float o0 = fmaxf(sv.x - bf2f(wv.x) + bv.x + fmaxf(h0r[0], 0.f), 0.f);
        float o1 = fmaxf(sv.y - bf2f(wv.y) + bv.y + fmaxf(h0r[1], 0.f), 0.f);
        float o2 = fmaxf(sv.z - bf2f(wv.z) + bv.z + fmaxf(h0r[2], 0.f), 0.f);
        float o3 = fmaxf(sv.w - bf2f(wv.w) + bv.w + fmaxf(h0r[3], 0.f), 0.f);
        ushort4 ov;
        ov.x = f2bf(o0); ov.y = f2bf(o1); ov.z = f2bf(o2); ov.w = f2bf(o3);
        ((ushort4*)h)[E * (HP / 4) + g] = ov;
    }
    for (int i = tid; i < 64 * 5; i += 256) {
        int e = i / 5, g = 75 + i % 5;
        ushort4 z = {0, 0, 0, 0};
        ((ushort4*)h)[(e0 + e) * (HP / 4) + g] = z;
    }
}

// K8: out[g] = pooled[g] @ W_ffn + b_ffn
__global__ __launch_bounds__(64) void ffn_out(
    const float* __restrict__ pooled, const float* __restrict__ W_ffn,
    const float* __restrict__ b_ffn, float* __restrict__ out)
{
    int g = blockIdx.x;
    int lane = threadIdx.x;
    float s = 0.f;
    for (int c = lane; c < HID; c += 64)
        s += pooled[(long)g * HID + c] * W_ffn[c];
    #pragma unroll
    for (int off = 32; off > 0; off >>= 1)
        s += __shfl_down(s, off, 64);
    if (lane == 0) out[g] = s + b_ffn[0];
}

extern "C" void kernel_launch(void* const* d_in, const int* in_sizes, int n_in,
                              void* d_out, int out_size, void* d_ws, size_t ws_size,
                              hipStream_t stream) {
    const float* x         = (const float*)d_in[0];
    const float* edge_attr = (const float*)d_in[1];
    const int*   edge_index= (const int*)d_in[2];
    const int*   batch     = (const int*)d_in[3];
    const float* W_init    = (const float*)d_in[4];
    const float* b_init    = (const float*)d_in[5];
    const float* W_convs   = (const float*)d_in[6];
    const float* b_convs   = (const float*)d_in[7];
    const float* W_e2n     = (const float*)d_in[8];
    const float* b_e2n     = (const float*)d_in[9];
    const float* W_ffn     = (const float*)d_in[10];
    const float* b_ffn     = (const float*)d_in[11];
    float* out = (float*)d_out;

    const int* row = edge_index;
    const int* col = edge_index + N_EDGES;
    const float* W2 = W_init + (size_t)F_NODE * HID;

    // Workspace (~255.3 MB). Aliases: hn reuses h's region (h dead after final
    // gather); Ab reuses xW1's region (xW1 dead after last edge_update).
    const size_t need = (size_t)N_EDGES * HP * 2 + (size_t)N_NODES * HID * 4 * 2
                      + (size_t)N_GRAPHS * HID * 4 + (size_t)N_NODES * 4 * 2
                      + (size_t)N_EDGES * 4 + (size_t)DEPTH * WFRAG_USHORT_PER_LAYER * 2
                      + (size_t)W2FRAG_USHORT * 2 + (size_t)(N_GRAPHS + 1 + N_GRAPHS) * 4
                      + 16384;
    if (ws_size < need) return;  // clean absmax fail, not a crash

    char* p = (char*)d_ws;
    auto take = [&](size_t bytes) {
        char* q = p;
        p += (bytes + 255) & ~(size_t)255;
        return q;
    };
    ushort_t* h       = (ushort_t*)take((size_t)N_EDGES * HP * 2);
    float*    S       = (float*)take((size_t)N_NODES * HID * 4);
    float*    xW1     = (float*)take((size_t)N_NODES * HID * 4);
    float*    pooled  = (float*)take((size_t)N_GRAPHS * HID * 4);
    int*      cursor  = (int*)take((size_t)N_NODES * 4);
    int*      offsets = (int*)take((size_t)N_NODES * 4);
    int*      eid     = (int*)take((size_t)N_EDGES * 4);
    ushort_t* wfrag   = (ushort_t*)take((size_t)DEPTH * WFRAG_USHORT_PER_LAYER * 2);
    ushort_t* wfrag2  = (ushort_t*)take((size_t)W2FRAG_USHORT * 2);
    int*      gdeg    = (int*)take((size_t)N_GRAPHS * 4);
    int*      goff    = (int*)take((size_t)(N_GRAPHS + 1) * 4);

    ushort_t* Ab = (ushort_t*)xW1;  // 15.36 MB <= 24 MB, used after xW1 dies
    float*    hn = (float*)h;       // 25.6 MB  <= 204.8 MB, used after h dies

    // CSR build (edges by col; graphs by sorted batch)
    hipMemsetAsync(cursor, 0, (size_t)N_NODES * 4, stream);
    hipMemsetAsync(gdeg, 0, (size_t)N_GRAPHS * 4, stream);
    csr_hist<<<N_EDGES / 256, 256, 0, stream>>>(col, cursor);
    csr_scan<<<1, 256, 0, stream>>>(cursor, offsets, cursor);
    csr_fill<<<N_EDGES / 256, 256, 0, stream>>>(col, cursor, eid);
    ghist<<<(N_NODES + 255) / 256, 256, 0, stream>>>(batch, gdeg);
    gscan<<<1, 128, 0, stream>>>(gdeg, goff);

    // W fragment pre-packs
    wfrag_build<<<dim3(10, NTILES, DEPTH), 64, 0, stream>>>(W_convs, wfrag);
    wfrag2_build<<<dim3(12, NTILES, 1), 64, 0, stream>>>(W_e2n, wfrag2);

    node_init_gemm<<<N_NODES / 16, 256, 0, stream>>>(x, W_init, b_init, xW1);
    h0_init<<<N_EDGES / 16, 256, 0, stream>>>(edge_attr, row, xW1, W_init, h);

    const int GS_GRID = ((N_NODES * 75) + 255) / 256;
    for (int l = 0; l < DEPTH; ++l) {
        gemm_mfma<<<N_EDGES / 64, 256, 0, stream>>>(
            h, wfrag + (size_t)l * WFRAG_USHORT_PER_LAYER, h);
        gather_sum<<<GS_GRID, 256, 0, stream>>>(h, offsets, cursor, eid, S);
        edge_update_tiled<<<N_EDGES / 64, 256, 0, stream>>>(
            h, S, xW1, edge_attr, W2, b_convs + l * HID, row);
    }

    // ---- e2n path: Ab = [bf16(x) | bf16(segsum(h)) | 0], hn = relu(Ab@W+b) ----
    x_fill<<<((N_NODES * 21) + 255) / 256, 256, 0, stream>>>(x, Ab);
    gather_ab<<<GS_GRID, 256, 0, stream>>>(h, offsets, cursor, eid, Ab);
    e2n_mfma<<<(N_NODES + 63) / 64, 256, 0, stream>>>(Ab, wfrag2, b_e2n, hn);
    pool_graph<<<N_GRAPHS, 256, 0, stream>>>(hn, goff, pooled);
    ffn_out<<<N_GRAPHS, 64, 0, stream>>>(pooled, W_ffn, b_ffn, out);
}

// Round 7
// 1819.498 us; speedup vs baseline: 3.9431x; 1.2752x over previous
//
#include <hip/hip_runtime.h>
#include <hip/hip_bf16.h>

typedef unsigned short ushort_t;
typedef __attribute__((ext_vector_type(8))) short short8;   // 8 bf16 = 4 VGPRs
typedef __attribute__((ext_vector_type(4))) float f32x4;    // MFMA C/D

#define N_NODES 20000
#define N_EDGES 320000
#define F_NODE 64
#define F_EDGE 16
#define HID 300
#define HP 320          // padded hidden: K-dim and row stride of h; 10 chunks of 32
#define NTILES 20       // padded N = 320 = 20 n-tiles of 16; 5 per wave (uniform)
#define DEPTH 3
#define N_GRAPHS 128
#define KE2N 384        // e2n K: 64 (x) + 300 (S) + 20 pad; 12 chunks of 32

#define WFRAG_USHORT_PER_LAYER (10 * NTILES * 64 * 8)  // 102400 ushorts
#define W2FRAG_USHORT (12 * NTILES * 64 * 8)           // 122880 ushorts

__device__ __forceinline__ float bf2f(ushort_t u) {
    union { unsigned int i; float f; } v;
    v.i = ((unsigned int)u) << 16;
    return v.f;
}
__device__ __forceinline__ ushort_t f2bf(float f) {
    union { float f; unsigned int i; } v;
    v.f = f;
    unsigned int x = v.i;
    unsigned int r = x + 0x7fffu + ((x >> 16) & 1u);  // RNE
    return (ushort_t)(r >> 16);
}

// ---------------- CSR build (col -> node adjacency) ----------------
__global__ __launch_bounds__(256) void csr_hist(
    const int* __restrict__ col, int* __restrict__ deg)
{
    int e = blockIdx.x * 256 + threadIdx.x;
    atomicAdd(&deg[col[e]], 1);
}

__global__ __launch_bounds__(256) void csr_scan(
    const int* __restrict__ deg, int* __restrict__ offsets,
    int* __restrict__ cursor)
{
    __shared__ int sums[256];
    const int t = threadIdx.x;
    const int CH = 79;  // 256*79 >= 20000
    int base = t * CH;
    int local = 0;
    for (int i = 0; i < CH; ++i) {
        int idx = base + i;
        if (idx < N_NODES) local += deg[idx];
    }
    sums[t] = local;
    __syncthreads();
    for (int off = 1; off < 256; off <<= 1) {
        int v = (t >= off) ? sums[t - off] : 0;
        __syncthreads();
        sums[t] += v;
        __syncthreads();
    }
    int run = (t > 0) ? sums[t - 1] : 0;
    for (int i = 0; i < CH; ++i) {
        int idx = base + i;
        if (idx < N_NODES) {
            offsets[idx] = run;
            cursor[idx] = run;
            run += deg[idx];
        }
    }
}

__global__ __launch_bounds__(256) void csr_fill(
    const int* __restrict__ col, int* __restrict__ cursor,
    int* __restrict__ eid)
{
    int e = blockIdx.x * 256 + threadIdx.x;
    int pos = atomicAdd(&cursor[col[e]], 1);
    eid[pos] = e;
}

// graph histogram over sorted batch
__global__ __launch_bounds__(256) void ghist(
    const int* __restrict__ batch, int* __restrict__ gdeg)
{
    int n = blockIdx.x * 256 + threadIdx.x;
    if (n < N_NODES) atomicAdd(&gdeg[batch[n]], 1);
}

__global__ __launch_bounds__(128) void gscan(
    const int* __restrict__ gdeg, int* __restrict__ goff)
{
    __shared__ int s[128];
    int t = threadIdx.x;
    int d = gdeg[t];
    s[t] = d;
    __syncthreads();
    for (int off = 1; off < 128; off <<= 1) {
        int v = (t >= off) ? s[t - off] : 0;
        __syncthreads();
        s[t] += v;
        __syncthreads();
    }
    goff[t] = s[t] - d;
    if (t == 127) goff[128] = s[127];
}

// ---------------- W fragment pre-pack ----------------
__global__ __launch_bounds__(64) void wfrag_build(
    const float* __restrict__ W_convs, ushort_t* __restrict__ wfrag)
{
    const int c = blockIdx.x, t = blockIdx.y, l = blockIdx.z;
    const int lane = threadIdx.x;
    const int k0 = c * 32 + (lane >> 4) * 8;
    const int n  = t * 16 + (lane & 15);
    ushort_t* dst = wfrag + (size_t)l * WFRAG_USHORT_PER_LAYER
                  + ((size_t)(c * NTILES + t) * 64 + lane) * 8;
    const float* Wl = W_convs + (size_t)l * HID * HID;
    #pragma unroll
    for (int j = 0; j < 8; ++j) {
        int k = k0 + j;
        float v = (k < HID && n < HID) ? Wl[(long)k * HID + n] : 0.f;
        dst[j] = f2bf(v);
    }
}

__global__ __launch_bounds__(64) void wfrag2_build(
    const float* __restrict__ W_e2n, ushort_t* __restrict__ wfrag2)
{
    const int c = blockIdx.x, t = blockIdx.y;
    const int lane = threadIdx.x;
    const int k0 = c * 32 + (lane >> 4) * 8;
    const int n  = t * 16 + (lane & 15);
    ushort_t* dst = wfrag2 + ((size_t)(c * NTILES + t) * 64 + lane) * 8;
    #pragma unroll
    for (int j = 0; j < 8; ++j) {
        int k = k0 + j;
        float v = (k < F_NODE + HID && n < HID) ? W_e2n[(long)k * HID + n] : 0.f;
        dst[j] = f2bf(v);
    }
}

// ---------------- kernels ----------------

// K1: xW1[n][c] = b_init[c] + sum_k x[n][k] * W_init[k][c]   (k < 64)
__global__ __launch_bounds__(256) void node_init_gemm(
    const float* __restrict__ x, const float* __restrict__ W_init,
    const float* __restrict__ b_init, float* __restrict__ xW1)
{
    __shared__ float xs[16 * 64];
    const int tid = threadIdx.x;
    const long n0 = (long)blockIdx.x * 16;
    for (int i = tid; i < 16 * 64; i += 256) xs[i] = x[n0 * 64 + i];
    __syncthreads();
    const int nl = tid >> 4, ct = tid & 15;
    for (int q = 0; q < 19; ++q) {
        int c = ct + 16 * q;
        if (c < HID) {
            float acc = b_init[c];
            #pragma unroll 8
            for (int k = 0; k < 64; ++k)
                acc = fmaf(xs[nl * 64 + k], W_init[(long)k * HID + c], acc);
            xW1[(n0 + nl) * HID + c] = acc;
        }
    }
}

// K2: h[e][c] = relu(xW1[row[e]][c] + edge_attr[e] @ W2);  h stride HP, zero pad
__global__ __launch_bounds__(256) void h0_init(
    const float* __restrict__ edge_attr, const int* __restrict__ row,
    const float* __restrict__ xW1, const float* __restrict__ W_init,
    ushort_t* __restrict__ h)
{
    __shared__ float W2s[16 * HID];
    __shared__ float eas[16 * 16];
    const int tid = threadIdx.x;
    const long e0 = (long)blockIdx.x * 16;
    for (int i = tid; i < 16 * HID; i += 256) {
        int k = i / HID, c = i % HID;
        W2s[i] = W_init[(long)(64 + k) * HID + c];
    }
    eas[tid] = edge_attr[e0 * 16 + tid];
    __syncthreads();
    const int el = tid >> 4, ct = tid & 15;
    const long e = e0 + el;
    const int r = row[e];
    float ea[16];
    #pragma unroll
    for (int k = 0; k < 16; ++k) ea[k] = eas[el * 16 + k];
    for (int q = 0; q < 20; ++q) {
        int c = ct + 16 * q;
        if (c < HID) {
            float acc = xW1[(long)r * HID + c];
            #pragma unroll
            for (int k = 0; k < 16; ++k)
                acc = fmaf(ea[k], W2s[k * HID + c], acc);
            acc = fmaxf(acc, 0.f);
            h[e * HP + c] = f2bf(acc);
        } else {
            h[e * HP + c] = 0;
        }
    }
}

// K3: IN-PLACE MFMA gemm  h <- h @ W.  No LDS: B-frags read directly from
// fragment-ordered wfrag (lane-consecutive 16B, L2-hot, zero reuse per block
// so staging bought nothing but 20 barrier drains). One barrier before the
// in-place stores.
__global__ __launch_bounds__(256) void gemm_mfma(
    const ushort_t* A, const ushort_t* __restrict__ wfrag_l, ushort_t* C)
{
    const int tid = threadIdx.x;
    const int wave = tid >> 6, lane = tid & 63;
    const int quad = lane >> 4, m = lane & 15;
    const long e0 = (long)blockIdx.x * 64;
    const int nt0 = wave * 5;

    f32x4 acc[5][4];
    #pragma unroll
    for (int t = 0; t < 5; ++t)
        #pragma unroll
        for (int mt = 0; mt < 4; ++mt)
            acc[t][mt] = (f32x4){0.f, 0.f, 0.f, 0.f};

    for (int c = 0; c < 10; ++c) {
        short8 a[4];
        #pragma unroll
        for (int mt = 0; mt < 4; ++mt)
            a[mt] = *(const short8*)(A + (e0 + mt * 16 + m) * HP + c * 32 + quad * 8);
        #pragma unroll
        for (int t = 0; t < 5; ++t) {
            short8 b = *(const short8*)(wfrag_l
                + ((size_t)(c * NTILES + nt0 + t) * 64 + lane) * 8);
            #pragma unroll
            for (int mt = 0; mt < 4; ++mt)
                acc[t][mt] = __builtin_amdgcn_mfma_f32_16x16x32_bf16(
                    a[mt], b, acc[t][mt], 0, 0, 0);
        }
    }
    __syncthreads();  // all waves' A reads complete before in-place stores

    #pragma unroll
    for (int t = 0; t < 5; ++t) {
        int col = (nt0 + t) * 16 + m;
        if (col >= HID) continue;
        #pragma unroll
        for (int mt = 0; mt < 4; ++mt) {
            long rbase = (e0 + mt * 16 + quad * 4) * HP + col;
            #pragma unroll
            for (int r = 0; r < 4; ++r)
                C[rbase + (long)r * HP] = f2bf(acc[t][mt][r]);
        }
    }
}

// K4: S[n][:] = sum over CSR edges of src[eid][:]   (fp32 out, 2-way ILP)
__global__ __launch_bounds__(256) void gather_sum(
    const ushort_t* __restrict__ src, const int* __restrict__ offsets,
    const int* __restrict__ ends, const int* __restrict__ eid,
    float* __restrict__ S)
{
    long idx = (long)blockIdx.x * 256 + threadIdx.x;
    if (idx >= (long)N_NODES * 75) return;
    int n = (int)(idx / 75);
    int g = (int)(idx % 75);
    int beg = offsets[n], end = ends[n];
    float a0 = 0.f, a1 = 0.f, a2 = 0.f, a3 = 0.f;
    float b0 = 0.f, b1 = 0.f, b2 = 0.f, b3 = 0.f;
    int j = beg;
    for (; j + 1 < end; j += 2) {
        int e0i = eid[j], e1i = eid[j + 1];
        ushort4 v0 = ((const ushort4*)src)[(long)e0i * (HP / 4) + g];
        ushort4 v1 = ((const ushort4*)src)[(long)e1i * (HP / 4) + g];
        a0 += bf2f(v0.x); a1 += bf2f(v0.y); a2 += bf2f(v0.z); a3 += bf2f(v0.w);
        b0 += bf2f(v1.x); b1 += bf2f(v1.y); b2 += bf2f(v1.z); b3 += bf2f(v1.w);
    }
    if (j < end) {
        int e0i = eid[j];
        ushort4 v0 = ((const ushort4*)src)[(long)e0i * (HP / 4) + g];
        a0 += bf2f(v0.x); a1 += bf2f(v0.y); a2 += bf2f(v0.z); a3 += bf2f(v0.w);
    }
    float4 o = {a0 + b0, a1 + b1, a2 + b2, a3 + b3};
    *(float4*)&S[(long)n * HID + 4 * g] = o;
}

// K4b: final gather -> bf16 directly into Ab cols 64..363 (stride KE2N)
__global__ __launch_bounds__(256) void gather_ab(
    const ushort_t* __restrict__ src, const int* __restrict__ offsets,
    const int* __restrict__ ends, const int* __restrict__ eid,
    ushort_t* __restrict__ Ab)
{
    long idx = (long)blockIdx.x * 256 + threadIdx.x;
    if (idx >= (long)N_NODES * 75) return;
    int n = (int)(idx / 75);
    int g = (int)(idx % 75);
    int beg = offsets[n], end = ends[n];
    float a0 = 0.f, a1 = 0.f, a2 = 0.f, a3 = 0.f;
    float b0 = 0.f, b1 = 0.f, b2 = 0.f, b3 = 0.f;
    int j = beg;
    for (; j + 1 < end; j += 2) {
        int e0i = eid[j], e1i = eid[j + 1];
        ushort4 v0 = ((const ushort4*)src)[(long)e0i * (HP / 4) + g];
        ushort4 v1 = ((const ushort4*)src)[(long)e1i * (HP / 4) + g];
        a0 += bf2f(v0.x); a1 += bf2f(v0.y); a2 += bf2f(v0.z); a3 += bf2f(v0.w);
        b0 += bf2f(v1.x); b1 += bf2f(v1.y); b2 += bf2f(v1.z); b3 += bf2f(v1.w);
    }
    if (j < end) {
        int e0i = eid[j];
        ushort4 v0 = ((const ushort4*)src)[(long)e0i * (HP / 4) + g];
        a0 += bf2f(v0.x); a1 += bf2f(v0.y); a2 += bf2f(v0.z); a3 += bf2f(v0.w);
    }
    ushort4 o;
    o.x = f2bf(a0 + b0); o.y = f2bf(a1 + b1);
    o.z = f2bf(a2 + b2); o.w = f2bf(a3 + b3);
    *(ushort4*)&Ab[(long)n * KE2N + 64 + 4 * g] = o;
}

// fill Ab cols 0..63 from x (bf16) and zero cols 364..383
__global__ __launch_bounds__(256) void x_fill(
    const float* __restrict__ x, ushort_t* __restrict__ Ab)
{
    long idx = (long)blockIdx.x * 256 + threadIdx.x;  // over N_NODES*21
    if (idx >= (long)N_NODES * 21) return;
    int n = (int)(idx / 21);
    int q = (int)(idx % 21);
    ushort4 o;
    if (q < 16) {
        float4 v = *(const float4*)&x[(long)n * 64 + 4 * q];
        o.x = f2bf(v.x); o.y = f2bf(v.y); o.z = f2bf(v.z); o.w = f2bf(v.w);
        *(ushort4*)&Ab[(long)n * KE2N + 4 * q] = o;
    } else {
        o.x = 0; o.y = 0; o.z = 0; o.w = 0;
        *(ushort4*)&Ab[(long)n * KE2N + 364 + 4 * (q - 16)] = o;
    }
}

// K7: hn = relu(Ab @ W_e2n + b)  via MFMA; no LDS, no barriers (C != A).
__global__ __launch_bounds__(256) void e2n_mfma(
    const ushort_t* __restrict__ Ab, const ushort_t* __restrict__ wfrag2,
    const float* __restrict__ b_e2n, float* __restrict__ hn)
{
    const int tid = threadIdx.x;
    const int wave = tid >> 6, lane = tid & 63;
    const int quad = lane >> 4, m = lane & 15;
    const long n0 = (long)blockIdx.x * 64;
    const int nt0 = wave * 5;

    f32x4 acc[5][4];
    #pragma unroll
    for (int t = 0; t < 5; ++t)
        #pragma unroll
        for (int mt = 0; mt < 4; ++mt)
            acc[t][mt] = (f32x4){0.f, 0.f, 0.f, 0.f};

    for (int c = 0; c < 12; ++c) {
        short8 a[4];
        #pragma unroll
        for (int mt = 0; mt < 4; ++mt) {
            long r = n0 + mt * 16 + m;
            if (r > N_NODES - 1) r = N_NODES - 1;  // clamp (stores masked)
            a[mt] = *(const short8*)(Ab + r * KE2N + c * 32 + quad * 8);
        }
        #pragma unroll
        for (int t = 0; t < 5; ++t) {
            short8 b = *(const short8*)(wfrag2
                + ((size_t)(c * NTILES + nt0 + t) * 64 + lane) * 8);
            #pragma unroll
            for (int mt = 0; mt < 4; ++mt)
                acc[t][mt] = __builtin_amdgcn_mfma_f32_16x16x32_bf16(
                    a[mt], b, acc[t][mt], 0, 0, 0);
        }
    }

    #pragma unroll
    for (int t = 0; t < 5; ++t) {
        int col = (nt0 + t) * 16 + m;
        if (col >= HID) continue;
        float bias = b_e2n[col];
        #pragma unroll
        for (int mt = 0; mt < 4; ++mt) {
            long rw = n0 + mt * 16 + quad * 4;
            #pragma unroll
            for (int r = 0; r < 4; ++r) {
                long rowi = rw + r;
                if (rowi < N_NODES)
                    hn[rowi * HP + col] = fmaxf(acc[t][mt][r] + bias, 0.f);
            }
        }
    }
}

// K7b: pooled[g][c] = sum of hn rows in [goff[g], goff[g+1])  (sorted batch)
__global__ __launch_bounds__(256) void pool_graph(
    const float* __restrict__ hn, const int* __restrict__ goff,
    float* __restrict__ pooled)
{
    int g = blockIdx.x;
    int beg = goff[g], end = goff[g + 1];
    for (int c = threadIdx.x; c < HID; c += 256) {
        float acc = 0.f;
        for (int n = beg; n < end; ++n)
            acc += hn[(long)n * HP + c];
        pooled[(long)g * HID + c] = acc;
    }
}

// K5: pair-threaded IN-PLACE edge update. One thread handles BOTH edges of a
// pair (2p, 2p+1) for one channel quad: reads both hW quads, computes both
// outputs, writes both -> all in-place deps thread-local, no LDS tile, no
// barrier. LDS = 4.3 KB -> wave-limited occupancy (was 32% with 45.5 KB).
//   h_new[e] = relu(S[row[e]] - hW[e^1] + bias + relu(xW1[row[e]] + ea[e]@W2))
__global__ __launch_bounds__(256) void edge_update_pairs(
    ushort_t* h, const float* __restrict__ S,
    const float* __restrict__ xW1, const float* __restrict__ edge_attr,
    const float* __restrict__ W2, const float* __restrict__ bias,
    const int* __restrict__ row)
{
    __shared__ float eas[64 * 16];      // 4 KB
    __shared__ int rows[64];
    const int tid = threadIdx.x;
    const long e0 = (long)blockIdx.x * 64;

    for (int i = tid; i < 64 * 16; i += 256)
        eas[i] = edge_attr[e0 * 16 + i];
    if (tid < 64) rows[tid] = row[e0 + tid];
    __syncthreads();

    for (int i = tid; i < 32 * 75; i += 256) {
        int p = i / 75, g = i % 75;
        int c0 = 4 * g;
        int la = 2 * p, lb = 2 * p + 1;      // local edge ids (pair)
        long Ea = e0 + la, Eb = e0 + lb;
        int ra = rows[la], rb = rows[lb];

        ushort4 wa = *(const ushort4*)&h[Ea * HP + c0];   // hW[2p]
        ushort4 wb = *(const ushort4*)&h[Eb * HP + c0];   // hW[2p+1]
        float4 sva = *(const float4*)&S[(long)ra * HID + c0];
        float4 svb = *(const float4*)&S[(long)rb * HID + c0];
        float4 xva = *(const float4*)&xW1[(long)ra * HID + c0];
        float4 xvb = *(const float4*)&xW1[(long)rb * HID + c0];
        float4 bv  = *(const float4*)&bias[c0];

        float h0a[4] = {xva.x, xva.y, xva.z, xva.w};
        float h0b[4] = {xvb.x, xvb.y, xvb.z, xvb.w};
        #pragma unroll
        for (int k = 0; k < 16; ++k) {
            float aa = eas[la * 16 + k];
            float ab = eas[lb * 16 + k];
            const float4 w = *(const float4*)&W2[(long)k * HID + c0];
            h0a[0] = fmaf(aa, w.x, h0a[0]); h0b[0] = fmaf(ab, w.x, h0b[0]);
            h0a[1] = fmaf(aa, w.y, h0a[1]); h0b[1] = fmaf(ab, w.y, h0b[1]);
            h0a[2] = fmaf(aa, w.z, h0a[2]); h0b[2] = fmaf(ab, w.z, h0b[2]);
            h0a[3] = fmaf(aa, w.w, h0a[3]); h0b[3] = fmaf(ab, w.w, h0b[3]);
        }
        // edge 2p uses reverse hW[2p+1]; edge 2p+1 uses hW[2p]
        float oa0 = fmaxf(sva.x - bf2f(wb.x) + bv.x + fmaxf(h0a[0], 0.f), 0.f);
        float oa1 = fmaxf(sva.y - bf2f(wb.y) + bv.y + fmaxf(h0a[1], 0.f), 0.f);
        float oa2 = fmaxf(sva.z - bf2f(wb.z) + bv.z + fmaxf(h0a[2], 0.f), 0.f);
        float oa3 = fmaxf(sva.w - bf2f(wb.w) + bv.w + fmaxf(h0a[3], 0.f), 0.f);
        float ob0 = fmaxf(svb.x - bf2f(wa.x) + bv.x + fmaxf(h0b[0], 0.f), 0.f);
        float ob1 = fmaxf(svb.y - bf2f(wa.y) + bv.y + fmaxf(h0b[1], 0.f), 0.f);
        float ob2 = fmaxf(svb.z - bf2f(wa.z) + bv.z + fmaxf(h0b[2], 0.f), 0.f);
        float ob3 = fmaxf(svb.w - bf2f(wa.w) + bv.w + fmaxf(h0b[3], 0.f), 0.f);
        ushort4 ova, ovb;
        ova.x = f2bf(oa0); ova.y = f2bf(oa1); ova.z = f2bf(oa2); ova.w = f2bf(oa3);
        ovb.x = f2bf(ob0); ovb.y = f2bf(ob1); ovb.z = f2bf(ob2); ovb.w = f2bf(ob3);
        ((ushort4*)h)[Ea * (HP / 4) + g] = ova;
        ((ushort4*)h)[Eb * (HP / 4) + g] = ovb;
    }
    // keep zero-pad invariant for cols 300..319 (write-only quads, race-free)
    for (int i = tid; i < 64 * 5; i += 256) {
        int e = i / 5, g = 75 + i % 5;
        ushort4 z = {0, 0, 0, 0};
        ((ushort4*)h)[(e0 + e) * (HP / 4) + g] = z;
    }
}

// K8: out[g] = pooled[g] @ W_ffn + b_ffn
__global__ __launch_bounds__(64) void ffn_out(
    const float* __restrict__ pooled, const float* __restrict__ W_ffn,
    const float* __restrict__ b_ffn, float* __restrict__ out)
{
    int g = blockIdx.x;
    int lane = threadIdx.x;
    float s = 0.f;
    for (int c = lane; c < HID; c += 64)
        s += pooled[(long)g * HID + c] * W_ffn[c];
    #pragma unroll
    for (int off = 32; off > 0; off >>= 1)
        s += __shfl_down(s, off, 64);
    if (lane == 0) out[g] = s + b_ffn[0];
}

extern "C" void kernel_launch(void* const* d_in, const int* in_sizes, int n_in,
                              void* d_out, int out_size, void* d_ws, size_t ws_size,
                              hipStream_t stream) {
    const float* x         = (const float*)d_in[0];
    const float* edge_attr = (const float*)d_in[1];
    const int*   edge_index= (const int*)d_in[2];
    const int*   batch     = (const int*)d_in[3];
    const float* W_init    = (const float*)d_in[4];
    const float* b_init    = (const float*)d_in[5];
    const float* W_convs   = (const float*)d_in[6];
    const float* b_convs   = (const float*)d_in[7];
    const float* W_e2n     = (const float*)d_in[8];
    const float* b_e2n     = (const float*)d_in[9];
    const float* W_ffn     = (const float*)d_in[10];
    const float* b_ffn     = (const float*)d_in[11];
    float* out = (float*)d_out;

    const int* row = edge_index;
    const int* col = edge_index + N_EDGES;
    const float* W2 = W_init + (size_t)F_NODE * HID;

    // Workspace (~255.3 MB). Aliases: hn reuses h's region (h dead after final
    // gather); Ab reuses xW1's region (xW1 dead after last edge_update).
    const size_t need = (size_t)N_EDGES * HP * 2 + (size_t)N_NODES * HID * 4 * 2
                      + (size_t)N_GRAPHS * HID * 4 + (size_t)N_NODES * 4 * 2
                      + (size_t)N_EDGES * 4 + (size_t)DEPTH * WFRAG_USHORT_PER_LAYER * 2
                      + (size_t)W2FRAG_USHORT * 2 + (size_t)(N_GRAPHS + 1 + N_GRAPHS) * 4
                      + 16384;
    if (ws_size < need) return;  // clean absmax fail, not a crash

    char* p = (char*)d_ws;
    auto take = [&](size_t bytes) {
        char* q = p;
        p += (bytes + 255) & ~(size_t)255;
        return q;
    };
    ushort_t* h       = (ushort_t*)take((size_t)N_EDGES * HP * 2);
    float*    S       = (float*)take((size_t)N_NODES * HID * 4);
    float*    xW1     = (float*)take((size_t)N_NODES * HID * 4);
    float*    pooled  = (float*)take((size_t)N_GRAPHS * HID * 4);
    int*      cursor  = (int*)take((size_t)N_NODES * 4);
    int*      offsets = (int*)take((size_t)N_NODES * 4);
    int*      eid     = (int*)take((size_t)N_EDGES * 4);
    ushort_t* wfrag   = (ushort_t*)take((size_t)DEPTH * WFRAG_USHORT_PER_LAYER * 2);
    ushort_t* wfrag2  = (ushort_t*)take((size_t)W2FRAG_USHORT * 2);
    int*      gdeg    = (int*)take((size_t)N_GRAPHS * 4);
    int*      goff    = (int*)take((size_t)(N_GRAPHS + 1) * 4);

    ushort_t* Ab = (ushort_t*)xW1;  // 15.36 MB <= 24 MB, used after xW1 dies
    float*    hn = (float*)h;       // 25.6 MB  <= 204.8 MB, used after h dies

    // CSR build (edges by col; graphs by sorted batch)
    hipMemsetAsync(cursor, 0, (size_t)N_NODES * 4, stream);
    hipMemsetAsync(gdeg, 0, (size_t)N_GRAPHS * 4, stream);
    csr_hist<<<N_EDGES / 256, 256, 0, stream>>>(col, cursor);
    csr_scan<<<1, 256, 0, stream>>>(cursor, offsets, cursor);
    csr_fill<<<N_EDGES / 256, 256, 0, stream>>>(col, cursor, eid);
    ghist<<<(N_NODES + 255) / 256, 256, 0, stream>>>(batch, gdeg);
    gscan<<<1, 128, 0, stream>>>(gdeg, goff);

    // W fragment pre-packs
    wfrag_build<<<dim3(10, NTILES, DEPTH), 64, 0, stream>>>(W_convs, wfrag);
    wfrag2_build<<<dim3(12, NTILES, 1), 64, 0, stream>>>(W_e2n, wfrag2);

    node_init_gemm<<<N_NODES / 16, 256, 0, stream>>>(x, W_init, b_init, xW1);
    h0_init<<<N_EDGES / 16, 256, 0, stream>>>(edge_attr, row, xW1, W_init, h);

    const int GS_GRID = ((N_NODES * 75) + 255) / 256;
    for (int l = 0; l < DEPTH; ++l) {
        gemm_mfma<<<N_EDGES / 64, 256, 0, stream>>>(
            h, wfrag + (size_t)l * WFRAG_USHORT_PER_LAYER, h);
        gather_sum<<<GS_GRID, 256, 0, stream>>>(h, offsets, cursor, eid, S);
        edge_update_pairs<<<N_EDGES / 64, 256, 0, stream>>>(
            h, S, xW1, edge_attr, W2, b_convs + l * HID, row);
    }

    // ---- e2n path: Ab = [bf16(x) | bf16(segsum(h)) | 0], hn = relu(Ab@W+b) ----
    x_fill<<<((N_NODES * 21) + 255) / 256, 256, 0, stream>>>(x, Ab);
    gather_ab<<<GS_GRID, 256, 0, stream>>>(h, offsets, cursor, eid, Ab);
    e2n_mfma<<<(N_NODES + 63) / 64, 256, 0, stream>>>(Ab, wfrag2, b_e2n, hn);
    pool_graph<<<N_GRAPHS, 256, 0, stream>>>(hn, goff, pooled);
    ffn_out<<<N_GRAPHS, 64, 0, stream>>>(pooled, W_ffn, b_ffn, out);
}

// Round 8
// 1535.686 us; speedup vs baseline: 4.6718x; 1.1848x over previous
//
#include <hip/hip_runtime.h>
#include <hip/hip_bf16.h>

typedef unsigned short ushort_t;
typedef __attribute__((ext_vector_type(8))) short short8;   // 8 bf16 = 4 VGPRs
typedef __attribute__((ext_vector_type(4))) float f32x4;    // MFMA C/D

#define N_NODES 20000
#define N_EDGES 320000
#define F_NODE 64
#define F_EDGE 16
#define HID 300
#define HP 320          // padded hidden: K-dim and row stride of h; 10 chunks of 32
#define NTILES 20       // padded N = 320 = 20 n-tiles of 16; 5 per wave (uniform)
#define DEPTH 3
#define N_GRAPHS 128
#define KE2N 384        // e2n K: 64 (x) + 300 (S) + 20 pad; 12 chunks of 32
#define ATS 328         // LDS A-tile row stride in ushorts (656 B): banks 4(m+q)%32 -> uniform

#define WFRAG_USHORT_PER_LAYER (10 * NTILES * 64 * 8)  // 102400 ushorts
#define W2FRAG_USHORT (12 * NTILES * 64 * 8)           // 122880 ushorts

__device__ __forceinline__ float bf2f(ushort_t u) {
    union { unsigned int i; float f; } v;
    v.i = ((unsigned int)u) << 16;
    return v.f;
}
__device__ __forceinline__ ushort_t f2bf(float f) {
    union { float f; unsigned int i; } v;
    v.f = f;
    unsigned int x = v.i;
    unsigned int r = x + 0x7fffu + ((x >> 16) & 1u);  // RNE
    return (ushort_t)(r >> 16);
}

// ---------------- CSR build (col -> node adjacency) ----------------
__global__ __launch_bounds__(256) void csr_hist(
    const int* __restrict__ col, int* __restrict__ deg)
{
    int e = blockIdx.x * 256 + threadIdx.x;
    atomicAdd(&deg[col[e]], 1);
}

__global__ __launch_bounds__(256) void csr_scan(
    const int* __restrict__ deg, int* __restrict__ offsets,
    int* __restrict__ cursor)
{
    __shared__ int sums[256];
    const int t = threadIdx.x;
    const int CH = 79;  // 256*79 >= 20000
    int base = t * CH;
    int local = 0;
    for (int i = 0; i < CH; ++i) {
        int idx = base + i;
        if (idx < N_NODES) local += deg[idx];
    }
    sums[t] = local;
    __syncthreads();
    for (int off = 1; off < 256; off <<= 1) {
        int v = (t >= off) ? sums[t - off] : 0;
        __syncthreads();
        sums[t] += v;
        __syncthreads();
    }
    int run = (t > 0) ? sums[t - 1] : 0;
    for (int i = 0; i < CH; ++i) {
        int idx = base + i;
        if (idx < N_NODES) {
            offsets[idx] = run;
            cursor[idx] = run;
            run += deg[idx];
        }
    }
}

__global__ __launch_bounds__(256) void csr_fill(
    const int* __restrict__ col, int* __restrict__ cursor,
    int* __restrict__ eid)
{
    int e = blockIdx.x * 256 + threadIdx.x;
    int pos = atomicAdd(&cursor[col[e]], 1);
    eid[pos] = e;
}

// graph histogram over sorted batch
__global__ __launch_bounds__(256) void ghist(
    const int* __restrict__ batch, int* __restrict__ gdeg)
{
    int n = blockIdx.x * 256 + threadIdx.x;
    if (n < N_NODES) atomicAdd(&gdeg[batch[n]], 1);
}

__global__ __launch_bounds__(128) void gscan(
    const int* __restrict__ gdeg, int* __restrict__ goff)
{
    __shared__ int s[128];
    int t = threadIdx.x;
    int d = gdeg[t];
    s[t] = d;
    __syncthreads();
    for (int off = 1; off < 128; off <<= 1) {
        int v = (t >= off) ? s[t - off] : 0;
        __syncthreads();
        s[t] += v;
        __syncthreads();
    }
    goff[t] = s[t] - d;
    if (t == 127) goff[128] = s[127];
}

// ---------------- W fragment pre-pack ----------------
__global__ __launch_bounds__(64) void wfrag_build(
    const float* __restrict__ W_convs, ushort_t* __restrict__ wfrag)
{
    const int c = blockIdx.x, t = blockIdx.y, l = blockIdx.z;
    const int lane = threadIdx.x;
    const int k0 = c * 32 + (lane >> 4) * 8;
    const int n  = t * 16 + (lane & 15);
    ushort_t* dst = wfrag + (size_t)l * WFRAG_USHORT_PER_LAYER
                  + ((size_t)(c * NTILES + t) * 64 + lane) * 8;
    const float* Wl = W_convs + (size_t)l * HID * HID;
    #pragma unroll
    for (int j = 0; j < 8; ++j) {
        int k = k0 + j;
        float v = (k < HID && n < HID) ? Wl[(long)k * HID + n] : 0.f;
        dst[j] = f2bf(v);
    }
}

__global__ __launch_bounds__(64) void wfrag2_build(
    const float* __restrict__ W_e2n, ushort_t* __restrict__ wfrag2)
{
    const int c = blockIdx.x, t = blockIdx.y;
    const int lane = threadIdx.x;
    const int k0 = c * 32 + (lane >> 4) * 8;
    const int n  = t * 16 + (lane & 15);
    ushort_t* dst = wfrag2 + ((size_t)(c * NTILES + t) * 64 + lane) * 8;
    #pragma unroll
    for (int j = 0; j < 8; ++j) {
        int k = k0 + j;
        float v = (k < F_NODE + HID && n < HID) ? W_e2n[(long)k * HID + n] : 0.f;
        dst[j] = f2bf(v);
    }
}

// ---------------- kernels ----------------

// K1: xW1b[n][c] = bf16(b_init[c] + sum_k x[n][k] * W_init[k][c])   (k < 64)
__global__ __launch_bounds__(256) void node_init_gemm(
    const float* __restrict__ x, const float* __restrict__ W_init,
    const float* __restrict__ b_init, ushort_t* __restrict__ xW1b)
{
    __shared__ float xs[16 * 64];
    const int tid = threadIdx.x;
    const long n0 = (long)blockIdx.x * 16;
    for (int i = tid; i < 16 * 64; i += 256) xs[i] = x[n0 * 64 + i];
    __syncthreads();
    const int nl = tid >> 4, ct = tid & 15;
    for (int q = 0; q < 19; ++q) {
        int c = ct + 16 * q;
        if (c < HID) {
            float acc = b_init[c];
            #pragma unroll 8
            for (int k = 0; k < 64; ++k)
                acc = fmaf(xs[nl * 64 + k], W_init[(long)k * HID + c], acc);
            xW1b[(n0 + nl) * HID + c] = f2bf(acc);
        }
    }
}

// Fused K2+K3 (layer 0): build h0 tile in LDS, then MFMA h = h0 @ W0.
// h0[e][c] = relu(xW1b[row[e]][c] + ea[e] @ W2).  h global is write-only here.
__global__ __launch_bounds__(256) void fused_h0_gemm(
    ushort_t* h, const ushort_t* __restrict__ xW1b,
    const float* __restrict__ edge_attr, const float* __restrict__ W2,
    const int* __restrict__ row, const ushort_t* __restrict__ wfrag_l)
{
    __shared__ ushort_t At[64 * ATS];   // 41984 B
    __shared__ float eas[64 * 16];
    __shared__ int rows[64];
    const int tid = threadIdx.x;
    const long e0 = (long)blockIdx.x * 64;

    for (int i = tid; i < 64 * 16; i += 256)
        eas[i] = edge_attr[e0 * 16 + i];
    if (tid < 64) rows[tid] = row[e0 + tid];
    __syncthreads();

    for (int i = tid; i < 64 * 80; i += 256) {  // 20 iters
        int e = i / 80, g = i % 80;
        int c0 = 4 * g;
        ushort4 o;
        if (g < 75) {
            int r = rows[e];
            ushort4 xv = *(const ushort4*)&xW1b[(long)r * HID + c0];
            float h0r[4] = {bf2f(xv.x), bf2f(xv.y), bf2f(xv.z), bf2f(xv.w)};
            #pragma unroll
            for (int k = 0; k < 16; ++k) {
                float a = eas[e * 16 + k];
                const float4 w = *(const float4*)&W2[(long)k * HID + c0];
                h0r[0] = fmaf(a, w.x, h0r[0]);
                h0r[1] = fmaf(a, w.y, h0r[1]);
                h0r[2] = fmaf(a, w.z, h0r[2]);
                h0r[3] = fmaf(a, w.w, h0r[3]);
            }
            o.x = f2bf(fmaxf(h0r[0], 0.f)); o.y = f2bf(fmaxf(h0r[1], 0.f));
            o.z = f2bf(fmaxf(h0r[2], 0.f)); o.w = f2bf(fmaxf(h0r[3], 0.f));
        } else {
            o.x = 0; o.y = 0; o.z = 0; o.w = 0;
        }
        *(ushort4*)&At[e * ATS + c0] = o;
    }
    __syncthreads();

    const int wave = tid >> 6, lane = tid & 63;
    const int quad = lane >> 4, m = lane & 15;
    const int nt0 = wave * 5;
    f32x4 acc[5][4];
    #pragma unroll
    for (int t = 0; t < 5; ++t)
        #pragma unroll
        for (int mt = 0; mt < 4; ++mt)
            acc[t][mt] = (f32x4){0.f, 0.f, 0.f, 0.f};

    for (int c = 0; c < 10; ++c) {
        short8 a[4];
        #pragma unroll
        for (int mt = 0; mt < 4; ++mt)
            a[mt] = *(const short8*)&At[(mt * 16 + m) * ATS + c * 32 + quad * 8];
        #pragma unroll
        for (int t = 0; t < 5; ++t) {
            short8 b = *(const short8*)(wfrag_l
                + ((size_t)(c * NTILES + nt0 + t) * 64 + lane) * 8);
            #pragma unroll
            for (int mt = 0; mt < 4; ++mt)
                acc[t][mt] = __builtin_amdgcn_mfma_f32_16x16x32_bf16(
                    a[mt], b, acc[t][mt], 0, 0, 0);
        }
    }
    #pragma unroll
    for (int t = 0; t < 5; ++t) {
        int col = (nt0 + t) * 16 + m;
        if (col >= HID) continue;
        #pragma unroll
        for (int mt = 0; mt < 4; ++mt) {
            long rbase = (e0 + mt * 16 + quad * 4) * HP + col;
            #pragma unroll
            for (int r = 0; r < 4; ++r)
                h[rbase + (long)r * HP] = f2bf(acc[t][mt][r]);
        }
    }
}

// Fused K5+K3 (layers 1,2): edge-update the 64-edge tile into LDS, then MFMA.
//   hnew[e] = relu(Sb[row[e]] - hW[e^1] + relu(xW1b[row[e]] + ea[e]@W2))
// (bias folded into Sb).  hW read from global h (own rows only), new hW written
// in place after the barrier.
__global__ __launch_bounds__(256) void fused_update_gemm(
    ushort_t* h, const ushort_t* __restrict__ Sb,
    const ushort_t* __restrict__ xW1b, const float* __restrict__ edge_attr,
    const float* __restrict__ W2, const int* __restrict__ row,
    const ushort_t* __restrict__ wfrag_l)
{
    __shared__ ushort_t At[64 * ATS];   // 41984 B
    __shared__ float eas[64 * 16];
    __shared__ int rows[64];
    const int tid = threadIdx.x;
    const long e0 = (long)blockIdx.x * 64;

    for (int i = tid; i < 64 * 16; i += 256)
        eas[i] = edge_attr[e0 * 16 + i];
    if (tid < 64) rows[tid] = row[e0 + tid];
    __syncthreads();

    for (int i = tid; i < 32 * 80; i += 256) {  // 10 iters, pair p + quad g
        int p = i / 80, g = i % 80;
        int c0 = 4 * g;
        int la = 2 * p, lb = 2 * p + 1;
        ushort4 ova, ovb;
        if (g < 75) {
            long Ea = e0 + la, Eb = e0 + lb;
            int ra = rows[la], rb = rows[lb];
            ushort4 wa = *(const ushort4*)&h[Ea * HP + c0];
            ushort4 wb = *(const ushort4*)&h[Eb * HP + c0];
            ushort4 sa = *(const ushort4*)&Sb[(long)ra * HID + c0];
            ushort4 sb = *(const ushort4*)&Sb[(long)rb * HID + c0];
            ushort4 xa = *(const ushort4*)&xW1b[(long)ra * HID + c0];
            ushort4 xb = *(const ushort4*)&xW1b[(long)rb * HID + c0];
            float h0a[4] = {bf2f(xa.x), bf2f(xa.y), bf2f(xa.z), bf2f(xa.w)};
            float h0b[4] = {bf2f(xb.x), bf2f(xb.y), bf2f(xb.z), bf2f(xb.w)};
            #pragma unroll
            for (int k = 0; k < 16; ++k) {
                float aa = eas[la * 16 + k];
                float ab = eas[lb * 16 + k];
                const float4 w = *(const float4*)&W2[(long)k * HID + c0];
                h0a[0] = fmaf(aa, w.x, h0a[0]); h0b[0] = fmaf(ab, w.x, h0b[0]);
                h0a[1] = fmaf(aa, w.y, h0a[1]); h0b[1] = fmaf(ab, w.y, h0b[1]);
                h0a[2] = fmaf(aa, w.z, h0a[2]); h0b[2] = fmaf(ab, w.z, h0b[2]);
                h0a[3] = fmaf(aa, w.w, h0a[3]); h0b[3] = fmaf(ab, w.w, h0b[3]);
            }
            ova.x = f2bf(fmaxf(bf2f(sa.x) - bf2f(wb.x) + fmaxf(h0a[0], 0.f), 0.f));
            ova.y = f2bf(fmaxf(bf2f(sa.y) - bf2f(wb.y) + fmaxf(h0a[1], 0.f), 0.f));
            ova.z = f2bf(fmaxf(bf2f(sa.z) - bf2f(wb.z) + fmaxf(h0a[2], 0.f), 0.f));
            ova.w = f2bf(fmaxf(bf2f(sa.w) - bf2f(wb.w) + fmaxf(h0a[3], 0.f), 0.f));
            ovb.x = f2bf(fmaxf(bf2f(sb.x) - bf2f(wa.x) + fmaxf(h0b[0], 0.f), 0.f));
            ovb.y = f2bf(fmaxf(bf2f(sb.y) - bf2f(wa.y) + fmaxf(h0b[1], 0.f), 0.f));
            ovb.z = f2bf(fmaxf(bf2f(sb.z) - bf2f(wa.z) + fmaxf(h0b[2], 0.f), 0.f));
            ovb.w = f2bf(fmaxf(bf2f(sb.w) - bf2f(wa.w) + fmaxf(h0b[3], 0.f), 0.f));
        } else {
            ova.x = 0; ova.y = 0; ova.z = 0; ova.w = 0;
            ovb = ova;
        }
        *(ushort4*)&At[la * ATS + c0] = ova;
        *(ushort4*)&At[lb * ATS + c0] = ovb;
    }
    __syncthreads();   // all h reads done; A tile complete

    const int wave = tid >> 6, lane = tid & 63;
    const int quad = lane >> 4, m = lane & 15;
    const int nt0 = wave * 5;
    f32x4 acc[5][4];
    #pragma unroll
    for (int t = 0; t < 5; ++t)
        #pragma unroll
        for (int mt = 0; mt < 4; ++mt)
            acc[t][mt] = (f32x4){0.f, 0.f, 0.f, 0.f};

    for (int c = 0; c < 10; ++c) {
        short8 a[4];
        #pragma unroll
        for (int mt = 0; mt < 4; ++mt)
            a[mt] = *(const short8*)&At[(mt * 16 + m) * ATS + c * 32 + quad * 8];
        #pragma unroll
        for (int t = 0; t < 5; ++t) {
            short8 b = *(const short8*)(wfrag_l
                + ((size_t)(c * NTILES + nt0 + t) * 64 + lane) * 8);
            #pragma unroll
            for (int mt = 0; mt < 4; ++mt)
                acc[t][mt] = __builtin_amdgcn_mfma_f32_16x16x32_bf16(
                    a[mt], b, acc[t][mt], 0, 0, 0);
        }
    }
    #pragma unroll
    for (int t = 0; t < 5; ++t) {
        int col = (nt0 + t) * 16 + m;
        if (col >= HID) continue;
        #pragma unroll
        for (int mt = 0; mt < 4; ++mt) {
            long rbase = (e0 + mt * 16 + quad * 4) * HP + col;
            #pragma unroll
            for (int r = 0; r < 4; ++r)
                h[rbase + (long)r * HP] = f2bf(acc[t][mt][r]);
        }
    }
}

// K4: Sb[n][:] = bf16( bias[:] + sum over CSR edges of src[eid][:] )
__global__ __launch_bounds__(256) void gather_sum(
    const ushort_t* __restrict__ src, const int* __restrict__ offsets,
    const int* __restrict__ ends, const int* __restrict__ eid,
    const float* __restrict__ bias, ushort_t* __restrict__ Sb)
{
    long idx = (long)blockIdx.x * 256 + threadIdx.x;
    if (idx >= (long)N_NODES * 75) return;
    int n = (int)(idx / 75);
    int g = (int)(idx % 75);
    int beg = offsets[n], end = ends[n];
    float a0 = 0.f, a1 = 0.f, a2 = 0.f, a3 = 0.f;
    float b0 = 0.f, b1 = 0.f, b2 = 0.f, b3 = 0.f;
    int j = beg;
    for (; j + 1 < end; j += 2) {
        int e0i = eid[j], e1i = eid[j + 1];
        ushort4 v0 = ((const ushort4*)src)[(long)e0i * (HP / 4) + g];
        ushort4 v1 = ((const ushort4*)src)[(long)e1i * (HP / 4) + g];
        a0 += bf2f(v0.x); a1 += bf2f(v0.y); a2 += bf2f(v0.z); a3 += bf2f(v0.w);
        b0 += bf2f(v1.x); b1 += bf2f(v1.y); b2 += bf2f(v1.z); b3 += bf2f(v1.w);
    }
    if (j < end) {
        int e0i = eid[j];
        ushort4 v0 = ((const ushort4*)src)[(long)e0i * (HP / 4) + g];
        a0 += bf2f(v0.x); a1 += bf2f(v0.y); a2 += bf2f(v0.z); a3 += bf2f(v0.w);
    }
    float4 bv = *(const float4*)&bias[4 * g];
    ushort4 o;
    o.x = f2bf(a0 + b0 + bv.x); o.y = f2bf(a1 + b1 + bv.y);
    o.z = f2bf(a2 + b2 + bv.z); o.w = f2bf(a3 + b3 + bv.w);
    *(ushort4*)&Sb[(long)n * HID + 4 * g] = o;
}

// K4b: final gather -> bf16 directly into Ab cols 64..363 (stride KE2N, no bias)
__global__ __launch_bounds__(256) void gather_ab(
    const ushort_t* __restrict__ src, const int* __restrict__ offsets,
    const int* __restrict__ ends, const int* __restrict__ eid,
    ushort_t* __restrict__ Ab)
{
    long idx = (long)blockIdx.x * 256 + threadIdx.x;
    if (idx >= (long)N_NODES * 75) return;
    int n = (int)(idx / 75);
    int g = (int)(idx % 75);
    int beg = offsets[n], end = ends[n];
    float a0 = 0.f, a1 = 0.f, a2 = 0.f, a3 = 0.f;
    float b0 = 0.f, b1 = 0.f, b2 = 0.f, b3 = 0.f;
    int j = beg;
    for (; j + 1 < end; j += 2) {
        int e0i = eid[j], e1i = eid[j + 1];
        ushort4 v0 = ((const ushort4*)src)[(long)e0i * (HP / 4) + g];
        ushort4 v1 = ((const ushort4*)src)[(long)e1i * (HP / 4) + g];
        a0 += bf2f(v0.x); a1 += bf2f(v0.y); a2 += bf2f(v0.z); a3 += bf2f(v0.w);
        b0 += bf2f(v1.x); b1 += bf2f(v1.y); b2 += bf2f(v1.z); b3 += bf2f(v1.w);
    }
    if (j < end) {
        int e0i = eid[j];
        ushort4 v0 = ((const ushort4*)src)[(long)e0i * (HP / 4) + g];
        a0 += bf2f(v0.x); a1 += bf2f(v0.y); a2 += bf2f(v0.z); a3 += bf2f(v0.w);
    }
    ushort4 o;
    o.x = f2bf(a0 + b0); o.y = f2bf(a1 + b1);
    o.z = f2bf(a2 + b2); o.w = f2bf(a3 + b3);
    *(ushort4*)&Ab[(long)n * KE2N + 64 + 4 * g] = o;
}

// fill Ab cols 0..63 from x (bf16) and zero cols 364..383
__global__ __launch_bounds__(256) void x_fill(
    const float* __restrict__ x, ushort_t* __restrict__ Ab)
{
    long idx = (long)blockIdx.x * 256 + threadIdx.x;  // over N_NODES*21
    if (idx >= (long)N_NODES * 21) return;
    int n = (int)(idx / 21);
    int q = (int)(idx % 21);
    ushort4 o;
    if (q < 16) {
        float4 v = *(const float4*)&x[(long)n * 64 + 4 * q];
        o.x = f2bf(v.x); o.y = f2bf(v.y); o.z = f2bf(v.z); o.w = f2bf(v.w);
        *(ushort4*)&Ab[(long)n * KE2N + 4 * q] = o;
    } else {
        o.x = 0; o.y = 0; o.z = 0; o.w = 0;
        *(ushort4*)&Ab[(long)n * KE2N + 364 + 4 * (q - 16)] = o;
    }
}

// K7: hn = relu(Ab @ W_e2n + b)  via MFMA; no LDS, no barriers (C != A).
__global__ __launch_bounds__(256) void e2n_mfma(
    const ushort_t* __restrict__ Ab, const ushort_t* __restrict__ wfrag2,
    const float* __restrict__ b_e2n, float* __restrict__ hn)
{
    const int tid = threadIdx.x;
    const int wave = tid >> 6, lane = tid & 63;
    const int quad = lane >> 4, m = lane & 15;
    const long n0 = (long)blockIdx.x * 64;
    const int nt0 = wave * 5;

    f32x4 acc[5][4];
    #pragma unroll
    for (int t = 0; t < 5; ++t)
        #pragma unroll
        for (int mt = 0; mt < 4; ++mt)
            acc[t][mt] = (f32x4){0.f, 0.f, 0.f, 0.f};

    for (int c = 0; c < 12; ++c) {
        short8 a[4];
        #pragma unroll
        for (int mt = 0; mt < 4; ++mt) {
            long r = n0 + mt * 16 + m;
            if (r > N_NODES - 1) r = N_NODES - 1;  // clamp (stores masked)
            a[mt] = *(const short8*)(Ab + r * KE2N + c * 32 + quad * 8);
        }
        #pragma unroll
        for (int t = 0; t < 5; ++t) {
            short8 b = *(const short8*)(wfrag2
                + ((size_t)(c * NTILES + nt0 + t) * 64 + lane) * 8);
            #pragma unroll
            for (int mt = 0; mt < 4; ++mt)
                acc[t][mt] = __builtin_amdgcn_mfma_f32_16x16x32_bf16(
                    a[mt], b, acc[t][mt], 0, 0, 0);
        }
    }

    #pragma unroll
    for (int t = 0; t < 5; ++t) {
        int col = (nt0 + t) * 16 + m;
        if (col >= HID) continue;
        float bias = b_e2n[col];
        #pragma unroll
        for (int mt = 0; mt < 4; ++mt) {
            long rw = n0 + mt * 16 + quad * 4;
            #pragma unroll
            for (int r = 0; r < 4; ++r) {
                long rowi = rw + r;
                if (rowi < N_NODES)
                    hn[rowi * HP + col] = fmaxf(acc[t][mt][r] + bias, 0.f);
            }
        }
    }
}

// K7b: pooled[g][c] = sum of hn rows in [goff[g], goff[g+1])  (sorted batch)
__global__ __launch_bounds__(256) void pool_graph(
    const float* __restrict__ hn, const int* __restrict__ goff,
    float* __restrict__ pooled)
{
    int g = blockIdx.x;
    int beg = goff[g], end = goff[g + 1];
    for (int c = threadIdx.x; c < HID; c += 256) {
        float acc = 0.f;
        for (int n = beg; n < end; ++n)
            acc += hn[(long)n * HP + c];
        pooled[(long)g * HID + c] = acc;
    }
}

// K5 (final layer only): standalone pair-threaded in-place edge update.
// Sb has bias folded; xW1b/Sb bf16.  Writes cols < 300 only (global pad cols
// are never read by anyone: all gemm A-tiles come from LDS now).
__global__ __launch_bounds__(256) void edge_update_pairs(
    ushort_t* h, const ushort_t* __restrict__ Sb,
    const ushort_t* __restrict__ xW1b, const float* __restrict__ edge_attr,
    const float* __restrict__ W2, const int* __restrict__ row)
{
    __shared__ float eas[64 * 16];
    __shared__ int rows[64];
    const int tid = threadIdx.x;
    const long e0 = (long)blockIdx.x * 64;

    for (int i = tid; i < 64 * 16; i += 256)
        eas[i] = edge_attr[e0 * 16 + i];
    if (tid < 64) rows[tid] = row[e0 + tid];
    __syncthreads();

    for (int i = tid; i < 32 * 75; i += 256) {
        int p = i / 75, g = i % 75;
        int c0 = 4 * g;
        int la = 2 * p, lb = 2 * p + 1;
        long Ea = e0 + la, Eb = e0 + lb;
        int ra = rows[la], rb = rows[lb];

        ushort4 wa = *(const ushort4*)&h[Ea * HP + c0];
        ushort4 wb = *(const ushort4*)&h[Eb * HP + c0];
        ushort4 sa = *(const ushort4*)&Sb[(long)ra * HID + c0];
        ushort4 sb = *(const ushort4*)&Sb[(long)rb * HID + c0];
        ushort4 xa = *(const ushort4*)&xW1b[(long)ra * HID + c0];
        ushort4 xb = *(const ushort4*)&xW1b[(long)rb * HID + c0];

        float h0a[4] = {bf2f(xa.x), bf2f(xa.y), bf2f(xa.z), bf2f(xa.w)};
        float h0b[4] = {bf2f(xb.x), bf2f(xb.y), bf2f(xb.z), bf2f(xb.w)};
        #pragma unroll
        for (int k = 0; k < 16; ++k) {
            float aa = eas[la * 16 + k];
            float ab = eas[lb * 16 + k];
            const float4 w = *(const float4*)&W2[(long)k * HID + c0];
            h0a[0] = fmaf(aa, w.x, h0a[0]); h0b[0] = fmaf(ab, w.x, h0b[0]);
            h0a[1] = fmaf(aa, w.y, h0a[1]); h0b[1] = fmaf(ab, w.y, h0b[1]);
            h0a[2] = fmaf(aa, w.z, h0a[2]); h0b[2] = fmaf(ab, w.z, h0b[2]);
            h0a[3] = fmaf(aa, w.w, h0a[3]); h0b[3] = fmaf(ab, w.w, h0b[3]);
        }
        ushort4 ova, ovb;
        ova.x = f2bf(fmaxf(bf2f(sa.x) - bf2f(wb.x) + fmaxf(h0a[0], 0.f), 0.f));
        ova.y = f2bf(fmaxf(bf2f(sa.y) - bf2f(wb.y) + fmaxf(h0a[1], 0.f), 0.f));
        ova.z = f2bf(fmaxf(bf2f(sa.z) - bf2f(wb.z) + fmaxf(h0a[2], 0.f), 0.f));
        ova.w = f2bf(fmaxf(bf2f(sa.w) - bf2f(wb.w) + fmaxf(h0a[3], 0.f), 0.f));
        ovb.x = f2bf(fmaxf(bf2f(sb.x) - bf2f(wa.x) + fmaxf(h0b[0], 0.f), 0.f));
        ovb.y = f2bf(fmaxf(bf2f(sb.y) - bf2f(wa.y) + fmaxf(h0b[1], 0.f), 0.f));
        ovb.z = f2bf(fmaxf(bf2f(sb.z) - bf2f(wa.z) + fmaxf(h0b[2], 0.f), 0.f));
        ovb.w = f2bf(fmaxf(bf2f(sb.w) - bf2f(wa.w) + fmaxf(h0b[3], 0.f), 0.f));
        ((ushort4*)h)[Ea * (HP / 4) + g] = ova;
        ((ushort4*)h)[Eb * (HP / 4) + g] = ovb;
    }
}

// K8: out[g] = pooled[g] @ W_ffn + b_ffn
__global__ __launch_bounds__(64) void ffn_out(
    const float* __restrict__ pooled, const float* __restrict__ W_ffn,
    const float* __restrict__ b_ffn, float* __restrict__ out)
{
    int g = blockIdx.x;
    int lane = threadIdx.x;
    float s = 0.f;
    for (int c = lane; c < HID; c += 64)
        s += pooled[(long)g * HID + c] * W_ffn[c];
    #pragma unroll
    for (int off = 32; off > 0; off >>= 1)
        s += __shfl_down(s, off, 64);
    if (lane == 0) out[g] = s + b_ffn[0];
}

extern "C" void kernel_launch(void* const* d_in, const int* in_sizes, int n_in,
                              void* d_out, int out_size, void* d_ws, size_t ws_size,
                              hipStream_t stream) {
    const float* x         = (const float*)d_in[0];
    const float* edge_attr = (const float*)d_in[1];
    const int*   edge_index= (const int*)d_in[2];
    const int*   batch     = (const int*)d_in[3];
    const float* W_init    = (const float*)d_in[4];
    const float* b_init    = (const float*)d_in[5];
    const float* W_convs   = (const float*)d_in[6];
    const float* b_convs   = (const float*)d_in[7];
    const float* W_e2n     = (const float*)d_in[8];
    const float* b_e2n     = (const float*)d_in[9];
    const float* W_ffn     = (const float*)d_in[10];
    const float* b_ffn     = (const float*)d_in[11];
    float* out = (float*)d_out;

    const int* row = edge_index;
    const int* col = edge_index + N_EDGES;
    const float* W2 = W_init + (size_t)F_NODE * HID;

    // Workspace (~247 MB): h 204.8M | Sb 12M | xW1b 12M | Ab 15.36M | pooled
    // 0.15M | cursor/offsets 0.16M | eid 1.28M | wfrag 0.61M | wfrag2 0.25M
    const size_t need = (size_t)N_EDGES * HP * 2
                      + (size_t)N_NODES * HID * 2 * 2          // Sb + xW1b
                      + (size_t)N_NODES * KE2N * 2             // Ab
                      + (size_t)N_GRAPHS * HID * 4
                      + (size_t)N_NODES * 4 * 2 + (size_t)N_EDGES * 4
                      + (size_t)DEPTH * WFRAG_USHORT_PER_LAYER * 2
                      + (size_t)W2FRAG_USHORT * 2
                      + (size_t)(N_GRAPHS + 1 + N_GRAPHS) * 4 + 16384;
    if (ws_size < need) return;  // clean absmax fail, not a crash

    char* p = (char*)d_ws;
    auto take = [&](size_t bytes) {
        char* q = p;
        p += (bytes + 255) & ~(size_t)255;
        return q;
    };
    ushort_t* h       = (ushort_t*)take((size_t)N_EDGES * HP * 2);
    ushort_t* Sb      = (ushort_t*)take((size_t)N_NODES * HID * 2);
    ushort_t* xW1b    = (ushort_t*)take((size_t)N_NODES * HID * 2);
    ushort_t* Ab      = (ushort_t*)take((size_t)N_NODES * KE2N * 2);
    float*    pooled  = (float*)take((size_t)N_GRAPHS * HID * 4);
    int*      cursor  = (int*)take((size_t)N_NODES * 4);
    int*      offsets = (int*)take((size_t)N_NODES * 4);
    int*      eid     = (int*)take((size_t)N_EDGES * 4);
    ushort_t* wfrag   = (ushort_t*)take((size_t)DEPTH * WFRAG_USHORT_PER_LAYER * 2);
    ushort_t* wfrag2  = (ushort_t*)take((size_t)W2FRAG_USHORT * 2);
    int*      gdeg    = (int*)take((size_t)N_GRAPHS * 4);
    int*      goff    = (int*)take((size_t)(N_GRAPHS + 1) * 4);

    float* hn = (float*)h;  // 25.6 MB <= 204.8 MB; h dead after gather_ab

    // CSR build (edges by col; graphs by sorted batch)
    hipMemsetAsync(cursor, 0, (size_t)N_NODES * 4, stream);
    hipMemsetAsync(gdeg, 0, (size_t)N_GRAPHS * 4, stream);
    csr_hist<<<N_EDGES / 256, 256, 0, stream>>>(col, cursor);
    csr_scan<<<1, 256, 0, stream>>>(cursor, offsets, cursor);
    csr_fill<<<N_EDGES / 256, 256, 0, stream>>>(col, cursor, eid);
    ghist<<<(N_NODES + 255) / 256, 256, 0, stream>>>(batch, gdeg);
    gscan<<<1, 128, 0, stream>>>(gdeg, goff);

    // W fragment pre-packs
    wfrag_build<<<dim3(10, NTILES, DEPTH), 64, 0, stream>>>(W_convs, wfrag);
    wfrag2_build<<<dim3(12, NTILES, 1), 64, 0, stream>>>(W_e2n, wfrag2);

    node_init_gemm<<<N_NODES / 16, 256, 0, stream>>>(x, W_init, b_init, xW1b);

    const int GS_GRID = ((N_NODES * 75) + 255) / 256;

    // layer 0: h0 built in LDS, gemm -> hW_0
    fused_h0_gemm<<<N_EDGES / 64, 256, 0, stream>>>(
        h, xW1b, edge_attr, W2, row, wfrag);
    gather_sum<<<GS_GRID, 256, 0, stream>>>(
        h, offsets, cursor, eid, b_convs + 0 * HID, Sb);
    // layers 1,2: update fused with gemm
    fused_update_gemm<<<N_EDGES / 64, 256, 0, stream>>>(
        h, Sb, xW1b, edge_attr, W2, row, wfrag + 1 * WFRAG_USHORT_PER_LAYER);
    gather_sum<<<GS_GRID, 256, 0, stream>>>(
        h, offsets, cursor, eid, b_convs + 1 * HID, Sb);
    fused_update_gemm<<<N_EDGES / 64, 256, 0, stream>>>(
        h, Sb, xW1b, edge_attr, W2, row, wfrag + 2 * (size_t)WFRAG_USHORT_PER_LAYER);
    gather_sum<<<GS_GRID, 256, 0, stream>>>(
        h, offsets, cursor, eid, b_convs + 2 * HID, Sb);
    // final standalone update -> h_3
    edge_update_pairs<<<N_EDGES / 64, 256, 0, stream>>>(
        h, Sb, xW1b, edge_attr, W2, row);

    // ---- e2n path ----
    x_fill<<<((N_NODES * 21) + 255) / 256, 256, 0, stream>>>(x, Ab);
    gather_ab<<<GS_GRID, 256, 0, stream>>>(h, offsets, cursor, eid, Ab);
    e2n_mfma<<<(N_NODES + 63) / 64, 256, 0, stream>>>(Ab, wfrag2, b_e2n, hn);
    pool_graph<<<N_GRAPHS, 256, 0, stream>>>(hn, goff, pooled);
    ffn_out<<<N_GRAPHS, 64, 0, stream>>>(pooled, W_ffn, b_ffn, out);
}